// Round 10
// baseline (188.703 us; speedup 1.0000x reference)
//
#include <hip/hip_runtime.h>
#include <math.h>

#define NB   2
#define SQ   2048
#define SMEM 512
#define SKVN 2560
#define ND   1024
#define NH   16
#define DHN  64
#define NBH  32                     /* NB*NH */

typedef unsigned short u16;
typedef short bf16x8 __attribute__((ext_vector_type(8)));   // 8 bf16 = 4 VGPR
typedef float f32x4 __attribute__((ext_vector_type(4)));
typedef u16 u16x4 __attribute__((ext_vector_type(4)));
typedef u16 u16x8 __attribute__((ext_vector_type(8)));

#define CSC   0.1803368801111204f   /* 0.125 * log2(e) */

__device__ __forceinline__ u16 f2bf(float f) {             // RNE f32->bf16
    unsigned u = __float_as_uint(f);
    u += 0x7FFFu + ((u >> 16) & 1u);
    return (u16)(u >> 16);
}

__device__ __forceinline__ void async16(u16* lds, const u16* g) {
    __builtin_amdgcn_global_load_lds(
        (const __attribute__((address_space(1))) void*)g,
        (__attribute__((address_space(3))) void*)lds, 16, 0, 0);
}

__device__ __forceinline__ unsigned lds_off(const void* p) {
    return (unsigned)(uintptr_t)(const __attribute__((address_space(3))) void*)p;
}

__device__ __forceinline__ u16x4 tr_read(unsigned a) {     // ds_read_b64_tr_b16
    u16x4 d;
    asm volatile("ds_read_b64_tr_b16 %0, %1" : "=v"(d) : "v"(a) : "memory");
    return d;
}

__device__ __forceinline__ unsigned cvtpk(float lo, float hi) {
    unsigned r;
    asm("v_cvt_pk_bf16_f32 %0, %1, %2" : "=v"(r) : "v"(lo), "v"(hi));
    return r;
}

__device__ __forceinline__ float exp2r(float x) {          // raw v_exp_f32
    float r;
    asm("v_exp_f32 %0, %1" : "=v"(r) : "v"(x));
    return r;
}

union PKU { unsigned u[2]; u16x4 v; };
union U8  { struct { u16x4 lo, hi; } p; bf16x8 v; };

// ---------------------------------------------------------------------------
// One launch: f32->bf16 for x, mems, Wq, Wk, Wv, Wo  (+ mask->log2-bias tail).
// ---------------------------------------------------------------------------
__global__ __launch_bounds__(256)
void cvt_all(const float* __restrict__ x, const float* __restrict__ mems,
             const float* __restrict__ W0, const float* __restrict__ W1,
             const float* __restrict__ W2, const float* __restrict__ W3,
             u16* __restrict__ xb, u16* __restrict__ memb,
             u16* __restrict__ d0, u16* __restrict__ d1,
             u16* __restrict__ d2, u16* __restrict__ d3,
             const int* __restrict__ mask, float* __restrict__ mbias)
{
    const int bid = blockIdx.x;
    if (bid >= 4608) {                       // mask bias tail: 5120 elems
        const int i = (bid - 4608) * 256 + threadIdx.x;
        if (i < NB * SKVN) mbias[i] = mask[i] ? 0.f : 1.0e6f * CSC;
        return;
    }
    size_t i = ((size_t)bid * 256 + threadIdx.x) * 8;
    const float* s; u16* d;
    if (i < 4194304) { s = x; d = xb; }
    else if (i < 5242880) { s = mems; d = memb; i -= 4194304; }
    else {
        size_t off = i - 5242880;
        const int wi = (int)(off >> 20);
        i = off & 1048575;
        switch (wi) {
            case 0:  s = W0; d = d0; break;
            case 1:  s = W1; d = d1; break;
            case 2:  s = W2; d = d2; break;
            default: s = W3; d = d3; break;
        }
    }
    float4 a = *(const float4*)(s + i);
    float4 b = *(const float4*)(s + i + 4);
    u16x8 o;
    o[0]=f2bf(a.x); o[1]=f2bf(a.y); o[2]=f2bf(a.z); o[3]=f2bf(a.w);
    o[4]=f2bf(b.x); o[5]=f2bf(b.y); o[6]=f2bf(b.z); o[7]=f2bf(b.w);
    *(u16x8*)(d + i) = o;
}

// A-row pointer with fused [mems; x] concat (NB=2 hardcoded)
__device__ __forceinline__ const u16* arow_ptr(const u16* x, const u16* mems,
                                               int grow, int T, int memLen) {
    int b = grow >= T ? 1 : 0;
    int t = grow - b * T;
    if (memLen > 0 && t < memLen)
        return mems + ((size_t)(b * memLen + t)) * ND;
    return x + ((size_t)(b * (T - memLen) + (t - memLen))) * ND;
}

// ---------------------------------------------------------------------------
// bf16 GEMM body (R6 form).
// ---------------------------------------------------------------------------
__device__ __forceinline__
void gemm_body(const u16* __restrict__ x, const u16* __restrict__ mems,
               const u16* __restrict__ W, const float* __restrict__ bias,
               void* __restrict__ out, int T, int memLen, int mode,
               int bx, int by, u16* As0, u16* As1, u16* Bs0, u16* Bs1)
{
    u16* As[2] = {As0, As1};
    u16* Bs[2] = {Bs0, Bs1};

    const int tid  = threadIdx.x;
    const int wave = tid >> 6, lane = tid & 63;
    const int lg = lane >> 4, li = lane & 15;
    const int wr = (wave >> 1) * 64, wc = (wave & 1) * 64;
    const int row0 = bx * 128, col0 = by * 128;

    const int srow = lane >> 2;
    const int sslot = lane & 3;

    f32x4 acc[4][4];
    const f32x4 zf = {0.f, 0.f, 0.f, 0.f};
#pragma unroll
    for (int m = 0; m < 4; ++m)
#pragma unroll
        for (int n = 0; n < 4; ++n) acc[m][n] = zf;

    auto stage = [&](int c, int kt) {
        const int k0 = kt * 32;
#pragma unroll
        for (int ch = wave; ch < 8; ch += 4) {
            const int r = ch * 16 + srow;
            const int gs = sslot ^ ((r ^ (r >> 2)) & 3);
            async16(&As[c][ch * 512],
                    arow_ptr(x, mems, row0 + r, T, memLen) + k0 + gs * 8);
        }
#pragma unroll
        for (int ch = wave; ch < 8; ch += 4) {
            const int r = ch * 16 + srow;
            const int gs = sslot ^ ((r ^ (r >> 2)) & 3);
            async16(&Bs[c][ch * 512],
                    W + (size_t)(col0 + r) * ND + k0 + gs * 8);
        }
    };

    stage(0, 0);
    int cur = 0;
    for (int kt = 0; kt < 32; ++kt) {
        __syncthreads();
        if (kt + 1 < 32) stage(cur ^ 1, kt + 1);

        bf16x8 af[4], bfr[4];
#pragma unroll
        for (int m = 0; m < 4; ++m) {
            const int r = wr + m * 16 + li;
            af[m] = *(const bf16x8*)&As[cur][r * 32 + ((lg ^ ((r ^ (r >> 2)) & 3)) << 3)];
        }
#pragma unroll
        for (int n = 0; n < 4; ++n) {
            const int r = wc + n * 16 + li;
            bfr[n] = *(const bf16x8*)&Bs[cur][r * 32 + ((lg ^ ((r ^ (r >> 2)) & 3)) << 3)];
        }
#pragma unroll
        for (int m = 0; m < 4; ++m)
#pragma unroll
            for (int n = 0; n < 4; ++n)
                acc[m][n] = __builtin_amdgcn_mfma_f32_16x16x32_bf16(
                                af[m], bfr[n], acc[m][n], 0, 0, 0);
        cur ^= 1;
    }

#pragma unroll
    for (int n = 0; n < 4; ++n) {
        const int col = col0 + wc + n * 16 + li;
        const float bv = bias[col];
#pragma unroll
        for (int m = 0; m < 4; ++m) {
            const int rbase = row0 + wr + m * 16 + 4 * lg;
            if (mode == 0) {
                float* o = (float*)out;
#pragma unroll
                for (int r = 0; r < 4; ++r)
                    o[(size_t)(rbase + r) * ND + col] = acc[m][n][r] + bv;
            } else if (mode == 1) {
                u16* o = (u16*)out;
                const int h = col >> 6, dh = col & 63;
#pragma unroll
                for (int r = 0; r < 4; ++r) {
                    const int grow = rbase + r;
                    const int b = grow >= T ? 1 : 0;
                    const int t = grow - b * T;
                    o[(((size_t)b * NH + h) * T + t) * DHN + dh] =
                        f2bf(acc[m][n][r] + bv);
                }
            } else {
                u16* o = (u16*)out;
                const int h = col >> 6, dh = col & 63;
                const int b = rbase >= T ? 1 : 0;
                const int t = rbase - b * T;
                u16x4 pk;
                pk[0] = f2bf(acc[m][n][0] + bv);
                pk[1] = f2bf(acc[m][n][1] + bv);
                pk[2] = f2bf(acc[m][n][2] + bv);
                pk[3] = f2bf(acc[m][n][3] + bv);
                *(u16x4*)&o[(((size_t)b * NH + h) * DHN + dh) * (size_t)T + t] = pk;
            }
        }
    }
}

// O-projection (single GEMM)
__global__ __launch_bounds__(256)
void gemm_single(const u16* __restrict__ x, const u16* __restrict__ W,
                 const float* __restrict__ bias, void* __restrict__ out,
                 int T, int mode)
{
    __shared__ u16 As[2][128 * 32];
    __shared__ u16 Bs[2][128 * 32];
    gemm_body(x, nullptr, W, bias, out, T, 0, mode, blockIdx.x, blockIdx.y,
              As[0], As[1], Bs[0], Bs[1]);
}

// Merged Q+K+V projections: 896 wg, XCD-bijective swizzle, id-decoded.
__global__ __launch_bounds__(256)
void gemm_qkv(const u16* __restrict__ xb, const u16* __restrict__ memb,
              const u16* __restrict__ Wq, const float* __restrict__ bq, u16* Qb,
              const u16* __restrict__ Wk, const float* __restrict__ bk, u16* Kb,
              const u16* __restrict__ Wv, const float* __restrict__ bv, u16* Vtb)
{
    __shared__ u16 As[2][128 * 32];
    __shared__ u16 Bs[2][128 * 32];
    const int id = (blockIdx.x & 7) * 112 + (blockIdx.x >> 3);  // 896 = 8*112
    if (id < 256) {
        gemm_body(xb, nullptr, Wq, bq, Qb, SQ, 0, 1, id & 31, id >> 5,
                  As[0], As[1], Bs[0], Bs[1]);
    } else if (id < 576) {
        const int t = id - 256;
        gemm_body(xb, memb, Wk, bk, Kb, SKVN, SMEM, 1, t % 40, t / 40,
                  As[0], As[1], Bs[0], Bs[1]);
    } else {
        const int t = id - 576;
        gemm_body(xb, memb, Wv, bv, Vtb, SKVN, SMEM, 2, t % 40, t / 40,
                  As[0], As[1], Bs[0], Bs[1]);
    }
}

// ---------------------------------------------------------------------------
// MFMA flash attention v7: 512 wgs (KV-split reverted), Q-tile 128/block.
// V LDS round-trip ELIMINATED: PV B-frags read directly from global Vt
// (L2-resident; loads issued at top of iteration, consumed at PV — overlap
// QK+softmax, never exposed to the barrier drain). LDS: K dbuf + P only.
// ---------------------------------------------------------------------------
__global__ __launch_bounds__(256)
void attn_mfma(const u16* __restrict__ Qw, const u16* __restrict__ Kw,
               const u16* __restrict__ Vt, const float* __restrict__ mbias,
               u16* __restrict__ AO)
{
    __shared__ u16 Ks[2][64 * 64];
    __shared__ u16 Ps[4][2048];          // per-wave: 2 P^T tiles [64 kv][16 q]

    const int tid  = threadIdx.x;
    const int wave = tid >> 6, lane = tid & 63;
    const int lg = lane >> 4, li = lane & 15;

    const int wg = blockIdx.x;                   // 512 wgs
    const int sw = (wg & 7) * 64 + (wg >> 3);    // XCD-contiguous chunks
    const int bh = sw >> 4;                      // 16 q-tiles per bh
    const int q0 = (sw & 15) * 128;
    const int b = bh >> 4, h = bh & 15;

    const u16* Kg = Kw + (size_t)bh * SKVN * DHN;
    const u16* Vg = Vt + (size_t)bh * DHN * SKVN;
    const float* mrow = mbias + (size_t)b * SKVN;

    // Q fragments: rows wave*32+li (half A) and +16 (half B)
    bf16x8 qA0, qA1, qB0, qB1;
    {
        const u16* Qp = Qw + ((size_t)bh * SQ + q0 + wave * 32 + li) * DHN;
        qA0 = *(const bf16x8*)(Qp + lg * 8);
        qA1 = *(const bf16x8*)(Qp + 32 + lg * 8);
        qB0 = *(const bf16x8*)(Qp + 16 * DHN + lg * 8);
        qB1 = *(const bf16x8*)(Qp + 16 * DHN + 32 + lg * 8);
    }

    U8 ou;
#pragma unroll
    for (int i = 0; i < 4; ++i) { ou.p.lo[i] = 0x3F80; ou.p.hi[i] = 0x3F80; }
    const bf16x8 onesb = ou.v;

    const int srow = lane >> 3, sslot = lane & 7;

    auto stage = [&](int c, int t) {             // K only now
        const int kv0 = t * 64;
#pragma unroll
        for (int ch = wave; ch < 8; ch += 4) {
            const int r = ch * 8 + srow;
            async16(&Ks[c][ch * 512],
                    Kg + (size_t)(kv0 + r) * DHN + ((sslot ^ (r & 7)) << 3));
        }
    };

    // V^T row pointers for the PV B-frags (identical bits to the old
    // swizzled-LDS path: vb_lo = Vt[r][kv0+8lg..], vb_hi = +32)
    const u16* Vr[4];
#pragma unroll
    for (int n = 0; n < 4; ++n)
        Vr[n] = Vg + (size_t)(n * 16 + li) * SKVN + 8 * lg;

    f32x4 oA[4], oB[4], laccA, laccB;
    const f32x4 zf = {0.f, 0.f, 0.f, 0.f};
#pragma unroll
    for (int n = 0; n < 4; ++n) { oA[n] = zf; oB[n] = zf; }
    laccA = zf; laccB = zf;

    u16* Pw = &Ps[wave][0];
    const unsigned paA = lds_off(Pw) + 256u * lg + 8u * li;
    const unsigned paB = paA + 2048u;            // half-B P^T tile

    float mbn[4];
#pragma unroll
    for (int n = 0; n < 4; ++n) mbn[n] = mrow[n * 16 + li];

    stage(0, 0);
    int cur = 0;
    for (int t = 0; t < SKVN / 64; ++t) {
        const int kv0 = t * 64;
        float mbc[4];
#pragma unroll
        for (int n = 0; n < 4; ++n) mbc[n] = mbn[n];

        __syncthreads();
        if (t + 1 < SKVN / 64) {
            stage(cur ^ 1, t + 1);
#pragma unroll
            for (int n = 0; n < 4; ++n)
                mbn[n] = mrow[(t + 1) * 64 + n * 16 + li];
        }

        // ---- V frags for THIS tile: global loads, overlap QK + softmax ----
        bf16x8 vl[4], vh[4];
#pragma unroll
        for (int n = 0; n < 4; ++n) {
            vl[n] = *(const bf16x8*)(Vr[n] + kv0);
            vh[n] = *(const bf16x8*)(Vr[n] + kv0 + 32);
        }

        // ---- S = Q K^T for both halves (K frags read once) ----
        __builtin_amdgcn_s_setprio(1);
        f32x4 sA[4], sB[4];
#pragma unroll
        for (int n = 0; n < 4; ++n) {
            const int r = n * 16 + li;
            bf16x8 kb0 = *(const bf16x8*)&Ks[cur][r * 64 + ((lg ^ (r & 7)) << 3)];
            bf16x8 kb1 = *(const bf16x8*)&Ks[cur][r * 64 + (((4 + lg) ^ (r & 7)) << 3)];
            f32x4 z = zf;
            z     = __builtin_amdgcn_mfma_f32_16x16x32_bf16(qA0, kb0, z, 0, 0, 0);
            sA[n] = __builtin_amdgcn_mfma_f32_16x16x32_bf16(qA1, kb1, z, 0, 0, 0);
            f32x4 y = zf;
            y     = __builtin_amdgcn_mfma_f32_16x16x32_bf16(qB0, kb0, y, 0, 0, 0);
            sB[n] = __builtin_amdgcn_mfma_f32_16x16x32_bf16(qB1, kb1, y, 0, 0, 0);
        }
        __builtin_amdgcn_s_setprio(0);

        // ---- P = exp2(s*CSC - mb); pack to the two P^T tiles ----
#pragma unroll
        for (int n = 0; n < 4; ++n) {
            const float mb = mbc[n];
            const int pw = (n * 16 + li) * 16 + lg * 4;
            PKU ua;
            ua.u[0] = cvtpk(exp2r(fmaf(sA[n][0], CSC, -mb)),
                            exp2r(fmaf(sA[n][1], CSC, -mb)));
            ua.u[1] = cvtpk(exp2r(fmaf(sA[n][2], CSC, -mb)),
                            exp2r(fmaf(sA[n][3], CSC, -mb)));
            *(u16x4*)&Pw[pw] = ua.v;
            PKU ub;
            ub.u[0] = cvtpk(exp2r(fmaf(sB[n][0], CSC, -mb)),
                            exp2r(fmaf(sB[n][1], CSC, -mb)));
            ub.u[1] = cvtpk(exp2r(fmaf(sB[n][2], CSC, -mb)),
                            exp2r(fmaf(sB[n][3], CSC, -mb)));
            *(u16x4*)&Pw[1024 + pw] = ub.v;
        }

        // ---- PV: A-frags via hardware transpose reads of both P^T tiles ----
        u16x4 a00 = tr_read(paA);
        u16x4 a01 = tr_read(paA + 128);
        u16x4 a10 = tr_read(paA + 1024);
        u16x4 a11 = tr_read(paA + 1024 + 128);
        u16x4 b00 = tr_read(paB);
        u16x4 b01 = tr_read(paB + 128);
        u16x4 b10 = tr_read(paB + 1024);
        u16x4 b11 = tr_read(paB + 1024 + 128);
        asm volatile("s_waitcnt lgkmcnt(0)" ::: "memory");
        __builtin_amdgcn_sched_barrier(0);
        U8 pA0, pA1, pB0, pB1;
        pA0.p.lo = a00; pA0.p.hi = a01;
        pA1.p.lo = a10; pA1.p.hi = a11;
        pB0.p.lo = b00; pB0.p.hi = b01;
        pB1.p.lo = b10; pB1.p.hi = b11;

        __builtin_amdgcn_s_setprio(1);
        laccA = __builtin_amdgcn_mfma_f32_16x16x32_bf16(pA0.v, onesb, laccA, 0, 0, 0);
        laccA = __builtin_amdgcn_mfma_f32_16x16x32_bf16(pA1.v, onesb, laccA, 0, 0, 0);
        laccB = __builtin_amdgcn_mfma_f32_16x16x32_bf16(pB0.v, onesb, laccB, 0, 0, 0);
        laccB = __builtin_amdgcn_mfma_f32_16x16x32_bf16(pB1.v, onesb, laccB, 0, 0, 0);
#pragma unroll
        for (int n = 0; n < 4; ++n) {
            oA[n] = __builtin_amdgcn_mfma_f32_16x16x32_bf16(pA0.v, vl[n], oA[n], 0, 0, 0);
            oA[n] = __builtin_amdgcn_mfma_f32_16x16x32_bf16(pA1.v, vh[n], oA[n], 0, 0, 0);
            oB[n] = __builtin_amdgcn_mfma_f32_16x16x32_bf16(pB0.v, vl[n], oB[n], 0, 0, 0);
            oB[n] = __builtin_amdgcn_mfma_f32_16x16x32_bf16(pB1.v, vh[n], oB[n], 0, 0, 0);
        }
        __builtin_amdgcn_s_setprio(0);
        cur ^= 1;
    }

    // epilogue: AO[b, q, h*64+d] bf16 — halves A and B
#pragma unroll
    for (int r = 0; r < 4; ++r) {
        const float invA = 1.f / laccA[r];
        const float invB = 1.f / laccB[r];
        const int rowA = q0 + wave * 32 + 4 * lg + r;
#pragma unroll
        for (int n = 0; n < 4; ++n) {
            const int col = h * DHN + n * 16 + li;
            AO[((size_t)b * SQ + rowA) * ND + col] = f2bf(oA[n][r] * invA);
            AO[((size_t)b * SQ + rowA + 16) * ND + col] = f2bf(oB[n][r] * invB);
        }
    }
}

// ---------------------------------------------------------------------------
extern "C" void kernel_launch(void* const* d_in, const int* in_sizes, int n_in,
                              void* d_out, int out_size, void* d_ws, size_t ws_size,
                              hipStream_t stream)
{
    const float* x    = (const float*)d_in[0];
    const float* mems = (const float*)d_in[1];
    const int*   mask = (const int*)d_in[3];
    const float* Wq = (const float*)d_in[4];  const float* bq = (const float*)d_in[5];
    const float* Wk = (const float*)d_in[6];  const float* bk = (const float*)d_in[7];
    const float* Wv = (const float*)d_in[8];  const float* bv = (const float*)d_in[9];
    const float* Wo = (const float*)d_in[10]; const float* bo = (const float*)d_in[11];
    float* out = (float*)d_out;

    u16* ws = (u16*)d_ws;
    u16* xb   = ws;
    u16* memb = xb   + (size_t)NB * SQ * ND;
    u16* Wqb  = memb + (size_t)NB * SMEM * ND;
    u16* Wkb  = Wqb + (size_t)ND * ND;
    u16* Wvb  = Wkb + (size_t)ND * ND;
    u16* Wob  = Wvb + (size_t)ND * ND;
    u16* Qb   = Wob + (size_t)ND * ND;
    u16* Kb   = Qb  + (size_t)NB * NH * SQ * DHN;
    u16* Vtb  = Kb  + (size_t)NB * NH * SKVN * DHN;
    u16* AOb  = Vtb + (size_t)NB * NH * SKVN * DHN;
    float* mbias = (float*)(AOb + (size_t)NB * SQ * ND);

    const dim3 blk(256);
    cvt_all<<<dim3(4628), blk, 0, stream>>>(x, mems, Wq, Wk, Wv, Wo,
                                            xb, memb, Wqb, Wkb, Wvb, Wob,
                                            mask, mbias);
    gemm_qkv<<<dim3(896), blk, 0, stream>>>(xb, memb,
                                            Wqb, bq, Qb,
                                            Wkb, bk, Kb,
                                            Wvb, bv, Vtb);
    attn_mfma<<<dim3(512), blk, 0, stream>>>(Qb, Kb, Vtb, mbias, AOb);
    gemm_single<<<dim3(32, 8), blk, 0, stream>>>(AOb, Wob, bo, (void*)out, SQ, 0);
}

// Round 11
// 165.721 us; speedup vs baseline: 1.1387x; 1.1387x over previous
//
#include <hip/hip_runtime.h>
#include <math.h>

#define NB   2
#define SQ   2048
#define SMEM 512
#define SKVN 2560
#define ND   1024
#define NH   16
#define DHN  64
#define NBH  32                     /* NB*NH */

typedef unsigned short u16;
typedef short bf16x8 __attribute__((ext_vector_type(8)));   // 8 bf16 = 4 VGPR
typedef float f32x4 __attribute__((ext_vector_type(4)));
typedef u16 u16x4 __attribute__((ext_vector_type(4)));
typedef u16 u16x8 __attribute__((ext_vector_type(8)));

#define CSC   0.1803368801111204f   /* 0.125 * log2(e) */

__device__ __forceinline__ u16 f2bf(float f) {             // RNE f32->bf16
    unsigned u = __float_as_uint(f);
    u += 0x7FFFu + ((u >> 16) & 1u);
    return (u16)(u >> 16);
}

__device__ __forceinline__ void async16(u16* lds, const u16* g) {
    __builtin_amdgcn_global_load_lds(
        (const __attribute__((address_space(1))) void*)g,
        (__attribute__((address_space(3))) void*)lds, 16, 0, 0);
}

__device__ __forceinline__ unsigned lds_off(const void* p) {
    return (unsigned)(uintptr_t)(const __attribute__((address_space(3))) void*)p;
}

__device__ __forceinline__ u16x4 tr_read(unsigned a) {     // ds_read_b64_tr_b16
    u16x4 d;
    asm volatile("ds_read_b64_tr_b16 %0, %1" : "=v"(d) : "v"(a) : "memory");
    return d;
}

__device__ __forceinline__ unsigned cvtpk(float lo, float hi) {
    unsigned r;
    asm("v_cvt_pk_bf16_f32 %0, %1, %2" : "=v"(r) : "v"(lo), "v"(hi));
    return r;
}

__device__ __forceinline__ float exp2r(float x) {          // raw v_exp_f32
    float r;
    asm("v_exp_f32 %0, %1" : "=v"(r) : "v"(x));
    return r;
}

union PKU { unsigned u[2]; u16x4 v; };
union U8  { struct { u16x4 lo, hi; } p; bf16x8 v; };

// ---------------------------------------------------------------------------
// One launch: f32->bf16 for x, mems, Wq, Wk, Wv, Wo  (+ mask->log2-bias tail).
// ---------------------------------------------------------------------------
__global__ __launch_bounds__(256)
void cvt_all(const float* __restrict__ x, const float* __restrict__ mems,
             const float* __restrict__ W0, const float* __restrict__ W1,
             const float* __restrict__ W2, const float* __restrict__ W3,
             u16* __restrict__ xb, u16* __restrict__ memb,
             u16* __restrict__ d0, u16* __restrict__ d1,
             u16* __restrict__ d2, u16* __restrict__ d3,
             const int* __restrict__ mask, float* __restrict__ mbias)
{
    const int bid = blockIdx.x;
    if (bid >= 4608) {                       // mask bias tail: 5120 elems
        const int i = (bid - 4608) * 256 + threadIdx.x;
        if (i < NB * SKVN) mbias[i] = mask[i] ? 0.f : 1.0e6f * CSC;
        return;
    }
    size_t i = ((size_t)bid * 256 + threadIdx.x) * 8;
    const float* s; u16* d;
    if (i < 4194304) { s = x; d = xb; }
    else if (i < 5242880) { s = mems; d = memb; i -= 4194304; }
    else {
        size_t off = i - 5242880;
        const int wi = (int)(off >> 20);
        i = off & 1048575;
        switch (wi) {
            case 0:  s = W0; d = d0; break;
            case 1:  s = W1; d = d1; break;
            case 2:  s = W2; d = d2; break;
            default: s = W3; d = d3; break;
        }
    }
    float4 a = *(const float4*)(s + i);
    float4 b = *(const float4*)(s + i + 4);
    u16x8 o;
    o[0]=f2bf(a.x); o[1]=f2bf(a.y); o[2]=f2bf(a.z); o[3]=f2bf(a.w);
    o[4]=f2bf(b.x); o[5]=f2bf(b.y); o[6]=f2bf(b.z); o[7]=f2bf(b.w);
    *(u16x8*)(d + i) = o;
}

// A-row pointer with fused [mems; x] concat (NB=2 hardcoded)
__device__ __forceinline__ const u16* arow_ptr(const u16* x, const u16* mems,
                                               int grow, int T, int memLen) {
    int b = grow >= T ? 1 : 0;
    int t = grow - b * T;
    if (memLen > 0 && t < memLen)
        return mems + ((size_t)(b * memLen + t)) * ND;
    return x + ((size_t)(b * (T - memLen) + (t - memLen))) * ND;
}

// ---------------------------------------------------------------------------
// bf16 GEMM body (R6 form, verified) — used by gemm_qkv.
// ---------------------------------------------------------------------------
__device__ __forceinline__
void gemm_body(const u16* __restrict__ x, const u16* __restrict__ mems,
               const u16* __restrict__ W, const float* __restrict__ bias,
               void* __restrict__ out, int T, int memLen, int mode,
               int bx, int by, u16* As0, u16* As1, u16* Bs0, u16* Bs1)
{
    u16* As[2] = {As0, As1};
    u16* Bs[2] = {Bs0, Bs1};

    const int tid  = threadIdx.x;
    const int wave = tid >> 6, lane = tid & 63;
    const int lg = lane >> 4, li = lane & 15;
    const int wr = (wave >> 1) * 64, wc = (wave & 1) * 64;
    const int row0 = bx * 128, col0 = by * 128;

    const int srow = lane >> 2;
    const int sslot = lane & 3;

    f32x4 acc[4][4];
    const f32x4 zf = {0.f, 0.f, 0.f, 0.f};
#pragma unroll
    for (int m = 0; m < 4; ++m)
#pragma unroll
        for (int n = 0; n < 4; ++n) acc[m][n] = zf;

    auto stage = [&](int c, int kt) {
        const int k0 = kt * 32;
#pragma unroll
        for (int ch = wave; ch < 8; ch += 4) {
            const int r = ch * 16 + srow;
            const int gs = sslot ^ ((r ^ (r >> 2)) & 3);
            async16(&As[c][ch * 512],
                    arow_ptr(x, mems, row0 + r, T, memLen) + k0 + gs * 8);
        }
#pragma unroll
        for (int ch = wave; ch < 8; ch += 4) {
            const int r = ch * 16 + srow;
            const int gs = sslot ^ ((r ^ (r >> 2)) & 3);
            async16(&Bs[c][ch * 512],
                    W + (size_t)(col0 + r) * ND + k0 + gs * 8);
        }
    };

    stage(0, 0);
    int cur = 0;
    for (int kt = 0; kt < 32; ++kt) {
        __syncthreads();
        if (kt + 1 < 32) stage(cur ^ 1, kt + 1);

        bf16x8 af[4], bfr[4];
#pragma unroll
        for (int m = 0; m < 4; ++m) {
            const int r = wr + m * 16 + li;
            af[m] = *(const bf16x8*)&As[cur][r * 32 + ((lg ^ ((r ^ (r >> 2)) & 3)) << 3)];
        }
#pragma unroll
        for (int n = 0; n < 4; ++n) {
            const int r = wc + n * 16 + li;
            bfr[n] = *(const bf16x8*)&Bs[cur][r * 32 + ((lg ^ ((r ^ (r >> 2)) & 3)) << 3)];
        }
#pragma unroll
        for (int m = 0; m < 4; ++m)
#pragma unroll
            for (int n = 0; n < 4; ++n)
                acc[m][n] = __builtin_amdgcn_mfma_f32_16x16x32_bf16(
                                af[m], bfr[n], acc[m][n], 0, 0, 0);
        cur ^= 1;
    }

#pragma unroll
    for (int n = 0; n < 4; ++n) {
        const int col = col0 + wc + n * 16 + li;
        const float bv = bias[col];
#pragma unroll
        for (int m = 0; m < 4; ++m) {
            const int rbase = row0 + wr + m * 16 + 4 * lg;
            if (mode == 1) {
                u16* o = (u16*)out;
                const int h = col >> 6, dh = col & 63;
#pragma unroll
                for (int r = 0; r < 4; ++r) {
                    const int grow = rbase + r;
                    const int b = grow >= T ? 1 : 0;
                    const int t = grow - b * T;
                    o[(((size_t)b * NH + h) * T + t) * DHN + dh] =
                        f2bf(acc[m][n][r] + bv);
                }
            } else {
                u16* o = (u16*)out;
                const int h = col >> 6, dh = col & 63;
                const int b = rbase >= T ? 1 : 0;
                const int t = rbase - b * T;
                u16x4 pk;
                pk[0] = f2bf(acc[m][n][0] + bv);
                pk[1] = f2bf(acc[m][n][1] + bv);
                pk[2] = f2bf(acc[m][n][2] + bv);
                pk[3] = f2bf(acc[m][n][3] + bv);
                *(u16x4*)&o[(((size_t)b * NH + h) * DHN + dh) * (size_t)T + t] = pk;
            }
        }
    }
}

// Merged Q+K+V projections: 896 wg, XCD-bijective swizzle, id-decoded.
__global__ __launch_bounds__(256)
void gemm_qkv(const u16* __restrict__ xb, const u16* __restrict__ memb,
              const u16* __restrict__ Wq, const float* __restrict__ bq, u16* Qb,
              const u16* __restrict__ Wk, const float* __restrict__ bk, u16* Kb,
              const u16* __restrict__ Wv, const float* __restrict__ bv, u16* Vtb)
{
    __shared__ u16 As[2][128 * 32];
    __shared__ u16 Bs[2][128 * 32];
    const int id = (blockIdx.x & 7) * 112 + (blockIdx.x >> 3);  // 896 = 8*112
    if (id < 256) {
        gemm_body(xb, nullptr, Wq, bq, Qb, SQ, 0, 1, id & 31, id >> 5,
                  As[0], As[1], Bs[0], Bs[1]);
    } else if (id < 576) {
        const int t = id - 256;
        gemm_body(xb, memb, Wk, bk, Kb, SKVN, SMEM, 1, t % 40, t / 40,
                  As[0], As[1], Bs[0], Bs[1]);
    } else {
        const int t = id - 576;
        gemm_body(xb, memb, Wv, bv, Vtb, SKVN, SMEM, 2, t % 40, t / 40,
                  As[0], As[1], Bs[0], Bs[1]);
    }
}

// ---------------------------------------------------------------------------
// O-projection: 64x128 tiles -> 512 wgs (2 blocks/CU; cross-block overlap
// hides the per-K-step barrier drain that capped the 256-wg version).
// acc[2][4] per wave; A: 1 staged chunk/wave, B: 2 chunks/wave.
// ---------------------------------------------------------------------------
__global__ __launch_bounds__(256)
void gemm_o(const u16* __restrict__ x, const u16* __restrict__ W,
            const float* __restrict__ bias, float* __restrict__ out)
{
    __shared__ u16 As[2][64 * 32];
    __shared__ u16 Bs[2][128 * 32];

    const int tid  = threadIdx.x;
    const int wave = tid >> 6, lane = tid & 63;
    const int lg = lane >> 4, li = lane & 15;
    const int wr = (wave >> 1) * 32, wc = (wave & 1) * 64;

    const int id = (blockIdx.x & 7) * 64 + (blockIdx.x >> 3);   // 512 = 8*64
    const int row0 = (id >> 3) * 64, col0 = (id & 7) * 128;

    const int srow = lane >> 2;
    const int sslot = lane & 3;

    f32x4 acc[2][4];
    const f32x4 zf = {0.f, 0.f, 0.f, 0.f};
#pragma unroll
    for (int m = 0; m < 2; ++m)
#pragma unroll
        for (int n = 0; n < 4; ++n) acc[m][n] = zf;

    auto stage = [&](int c, int kt) {
        const int k0 = kt * 32;
        {   // A: 4 chunks of 16 rows; one per wave
            const int r = wave * 16 + srow;
            const int gs = sslot ^ ((r ^ (r >> 2)) & 3);
            async16(&As[c][wave * 512],
                    x + (size_t)(row0 + r) * ND + k0 + gs * 8);
        }
#pragma unroll
        for (int ch = wave; ch < 8; ch += 4) {   // B: 8 chunks; two per wave
            const int r = ch * 16 + srow;
            const int gs = sslot ^ ((r ^ (r >> 2)) & 3);
            async16(&Bs[c][ch * 512],
                    W + (size_t)(col0 + r) * ND + k0 + gs * 8);
        }
    };

    stage(0, 0);
    int cur = 0;
    for (int kt = 0; kt < 32; ++kt) {
        __syncthreads();
        if (kt + 1 < 32) stage(cur ^ 1, kt + 1);

        bf16x8 af[2], bfr[4];
#pragma unroll
        for (int m = 0; m < 2; ++m) {
            const int r = wr + m * 16 + li;
            af[m] = *(const bf16x8*)&As[cur][r * 32 + ((lg ^ ((r ^ (r >> 2)) & 3)) << 3)];
        }
#pragma unroll
        for (int n = 0; n < 4; ++n) {
            const int r = wc + n * 16 + li;
            bfr[n] = *(const bf16x8*)&Bs[cur][r * 32 + ((lg ^ ((r ^ (r >> 2)) & 3)) << 3)];
        }
#pragma unroll
        for (int m = 0; m < 2; ++m)
#pragma unroll
            for (int n = 0; n < 4; ++n)
                acc[m][n] = __builtin_amdgcn_mfma_f32_16x16x32_bf16(
                                af[m], bfr[n], acc[m][n], 0, 0, 0);
        cur ^= 1;
    }

#pragma unroll
    for (int n = 0; n < 4; ++n) {
        const int col = col0 + wc + n * 16 + li;
        const float bv = bias[col];
#pragma unroll
        for (int m = 0; m < 2; ++m) {
            const int rbase = row0 + wr + m * 16 + 4 * lg;
#pragma unroll
            for (int r = 0; r < 4; ++r)
                out[(size_t)(rbase + r) * ND + col] = acc[m][n][r] + bv;
        }
    }
}

// ---------------------------------------------------------------------------
// MFMA flash attention (R8 config, verbatim): 512 wgs, Q-tile 128/block,
// K/V double-buffered in LDS, no-max softmax, MFMA row-sum, P^T + tr_read.
// ---------------------------------------------------------------------------
__global__ __launch_bounds__(256)
void attn_mfma(const u16* __restrict__ Qw, const u16* __restrict__ Kw,
               const u16* __restrict__ Vt, const float* __restrict__ mbias,
               u16* __restrict__ AO)
{
    __shared__ u16 Ks[2][64 * 64];
    __shared__ u16 Vs[2][64 * 64];
    __shared__ u16 Ps[4][2048];          // per-wave: 2 P^T tiles [64 kv][16 q]

    const int tid  = threadIdx.x;
    const int wave = tid >> 6, lane = tid & 63;
    const int lg = lane >> 4, li = lane & 15;

    const int wg = blockIdx.x;                   // 512 wgs
    const int sw = (wg & 7) * 64 + (wg >> 3);    // XCD-contiguous chunks
    const int bh = sw >> 4;                      // 16 q-tiles per bh
    const int q0 = (sw & 15) * 128;
    const int b = bh >> 4, h = bh & 15;

    const u16* Kg = Kw + (size_t)bh * SKVN * DHN;
    const u16* Vg = Vt + (size_t)bh * DHN * SKVN;
    const float* mrow = mbias + (size_t)b * SKVN;

    // Q fragments: rows wave*32+li (half A) and +16 (half B)
    bf16x8 qA0, qA1, qB0, qB1;
    {
        const u16* Qp = Qw + ((size_t)bh * SQ + q0 + wave * 32 + li) * DHN;
        qA0 = *(const bf16x8*)(Qp + lg * 8);
        qA1 = *(const bf16x8*)(Qp + 32 + lg * 8);
        qB0 = *(const bf16x8*)(Qp + 16 * DHN + lg * 8);
        qB1 = *(const bf16x8*)(Qp + 16 * DHN + 32 + lg * 8);
    }

    U8 ou;
#pragma unroll
    for (int i = 0; i < 4; ++i) { ou.p.lo[i] = 0x3F80; ou.p.hi[i] = 0x3F80; }
    const bf16x8 onesb = ou.v;

    const int srow = lane >> 3, sslot = lane & 7;

    auto stage = [&](int c, int t) {
        const int kv0 = t * 64;
#pragma unroll
        for (int ch = wave; ch < 8; ch += 4) {
            const int r = ch * 8 + srow;
            async16(&Ks[c][ch * 512],
                    Kg + (size_t)(kv0 + r) * DHN + ((sslot ^ (r & 7)) << 3));
        }
#pragma unroll
        for (int ch = wave; ch < 8; ch += 4) {
            const int r = ch * 8 + srow;
            async16(&Vs[c][ch * 512],
                    Vg + (size_t)r * SKVN + kv0 + ((sslot ^ (r & 7)) << 3));
        }
    };

    f32x4 oA[4], oB[4], laccA, laccB;
    const f32x4 zf = {0.f, 0.f, 0.f, 0.f};
#pragma unroll
    for (int n = 0; n < 4; ++n) { oA[n] = zf; oB[n] = zf; }
    laccA = zf; laccB = zf;

    u16* Pw = &Ps[wave][0];
    const unsigned paA = lds_off(Pw) + 256u * lg + 8u * li;
    const unsigned paB = paA + 2048u;            // half-B P^T tile

    float mbn[4];
#pragma unroll
    for (int n = 0; n < 4; ++n) mbn[n] = mrow[n * 16 + li];

    stage(0, 0);
    int cur = 0;
    for (int t = 0; t < SKVN / 64; ++t) {
        float mbc[4];
#pragma unroll
        for (int n = 0; n < 4; ++n) mbc[n] = mbn[n];

        __syncthreads();
        if (t + 1 < SKVN / 64) {
            stage(cur ^ 1, t + 1);
#pragma unroll
            for (int n = 0; n < 4; ++n)
                mbn[n] = mrow[(t + 1) * 64 + n * 16 + li];
        }

        // ---- S = Q K^T for both halves (K frags read once) ----
        __builtin_amdgcn_s_setprio(1);
        f32x4 sA[4], sB[4];
#pragma unroll
        for (int n = 0; n < 4; ++n) {
            const int r = n * 16 + li;
            bf16x8 kb0 = *(const bf16x8*)&Ks[cur][r * 64 + ((lg ^ (r & 7)) << 3)];
            bf16x8 kb1 = *(const bf16x8*)&Ks[cur][r * 64 + (((4 + lg) ^ (r & 7)) << 3)];
            f32x4 z = zf;
            z     = __builtin_amdgcn_mfma_f32_16x16x32_bf16(qA0, kb0, z, 0, 0, 0);
            sA[n] = __builtin_amdgcn_mfma_f32_16x16x32_bf16(qA1, kb1, z, 0, 0, 0);
            f32x4 y = zf;
            y     = __builtin_amdgcn_mfma_f32_16x16x32_bf16(qB0, kb0, y, 0, 0, 0);
            sB[n] = __builtin_amdgcn_mfma_f32_16x16x32_bf16(qB1, kb1, y, 0, 0, 0);
        }
        __builtin_amdgcn_s_setprio(0);

        // ---- P = exp2(s*CSC - mb); pack to the two P^T tiles ----
#pragma unroll
        for (int n = 0; n < 4; ++n) {
            const float mb = mbc[n];
            const int pw = (n * 16 + li) * 16 + lg * 4;
            PKU ua;
            ua.u[0] = cvtpk(exp2r(fmaf(sA[n][0], CSC, -mb)),
                            exp2r(fmaf(sA[n][1], CSC, -mb)));
            ua.u[1] = cvtpk(exp2r(fmaf(sA[n][2], CSC, -mb)),
                            exp2r(fmaf(sA[n][3], CSC, -mb)));
            *(u16x4*)&Pw[pw] = ua.v;
            PKU ub;
            ub.u[0] = cvtpk(exp2r(fmaf(sB[n][0], CSC, -mb)),
                            exp2r(fmaf(sB[n][1], CSC, -mb)));
            ub.u[1] = cvtpk(exp2r(fmaf(sB[n][2], CSC, -mb)),
                            exp2r(fmaf(sB[n][3], CSC, -mb)));
            *(u16x4*)&Pw[1024 + pw] = ub.v;
        }

        // ---- PV: A-frags via hardware transpose reads of both P^T tiles ----
        u16x4 a00 = tr_read(paA);
        u16x4 a01 = tr_read(paA + 128);
        u16x4 a10 = tr_read(paA + 1024);
        u16x4 a11 = tr_read(paA + 1024 + 128);
        u16x4 b00 = tr_read(paB);
        u16x4 b01 = tr_read(paB + 128);
        u16x4 b10 = tr_read(paB + 1024);
        u16x4 b11 = tr_read(paB + 1024 + 128);
        asm volatile("s_waitcnt lgkmcnt(0)" ::: "memory");
        __builtin_amdgcn_sched_barrier(0);
        U8 pA0, pA1, pB0, pB1;
        pA0.p.lo = a00; pA0.p.hi = a01;
        pA1.p.lo = a10; pA1.p.hi = a11;
        pB0.p.lo = b00; pB0.p.hi = b01;
        pB1.p.lo = b10; pB1.p.hi = b11;

        __builtin_amdgcn_s_setprio(1);
        laccA = __builtin_amdgcn_mfma_f32_16x16x32_bf16(pA0.v, onesb, laccA, 0, 0, 0);
        laccA = __builtin_amdgcn_mfma_f32_16x16x32_bf16(pA1.v, onesb, laccA, 0, 0, 0);
        laccB = __builtin_amdgcn_mfma_f32_16x16x32_bf16(pB0.v, onesb, laccB, 0, 0, 0);
        laccB = __builtin_amdgcn_mfma_f32_16x16x32_bf16(pB1.v, onesb, laccB, 0, 0, 0);
#pragma unroll
        for (int n = 0; n < 4; ++n) {
            const int r = n * 16 + li;
            bf16x8 vb0 = *(const bf16x8*)&Vs[cur][r * 64 + ((lg ^ (r & 7)) << 3)];
            bf16x8 vb1 = *(const bf16x8*)&Vs[cur][r * 64 + (((4 + lg) ^ (r & 7)) << 3)];
            oA[n] = __builtin_amdgcn_mfma_f32_16x16x32_bf16(pA0.v, vb0, oA[n], 0, 0, 0);
            oA[n] = __builtin_amdgcn_mfma_f32_16x16x32_bf16(pA1.v, vb1, oA[n], 0, 0, 0);
            oB[n] = __builtin_amdgcn_mfma_f32_16x16x32_bf16(pB0.v, vb0, oB[n], 0, 0, 0);
            oB[n] = __builtin_amdgcn_mfma_f32_16x16x32_bf16(pB1.v, vb1, oB[n], 0, 0, 0);
        }
        __builtin_amdgcn_s_setprio(0);
        cur ^= 1;
    }

    // epilogue: AO[b, q, h*64+d] bf16 — halves A and B
#pragma unroll
    for (int r = 0; r < 4; ++r) {
        const float invA = 1.f / laccA[r];
        const float invB = 1.f / laccB[r];
        const int rowA = q0 + wave * 32 + 4 * lg + r;
#pragma unroll
        for (int n = 0; n < 4; ++n) {
            const int col = h * DHN + n * 16 + li;
            AO[((size_t)b * SQ + rowA) * ND + col] = f2bf(oA[n][r] * invA);
            AO[((size_t)b * SQ + rowA + 16) * ND + col] = f2bf(oB[n][r] * invB);
        }
    }
}

// ---------------------------------------------------------------------------
extern "C" void kernel_launch(void* const* d_in, const int* in_sizes, int n_in,
                              void* d_out, int out_size, void* d_ws, size_t ws_size,
                              hipStream_t stream)
{
    const float* x    = (const float*)d_in[0];
    const float* mems = (const float*)d_in[1];
    const int*   mask = (const int*)d_in[3];
    const float* Wq = (const float*)d_in[4];  const float* bq = (const float*)d_in[5];
    const float* Wk = (const float*)d_in[6];  const float* bk = (const float*)d_in[7];
    const float* Wv = (const float*)d_in[8];  const float* bv = (const float*)d_in[9];
    const float* Wo = (const float*)d_in[10]; const float* bo = (const float*)d_in[11];
    float* out = (float*)d_out;

    u16* ws = (u16*)d_ws;
    u16* xb   = ws;
    u16* memb = xb   + (size_t)NB * SQ * ND;
    u16* Wqb  = memb + (size_t)NB * SMEM * ND;
    u16* Wkb  = Wqb + (size_t)ND * ND;
    u16* Wvb  = Wkb + (size_t)ND * ND;
    u16* Wob  = Wvb + (size_t)ND * ND;
    u16* Qb   = Wob + (size_t)ND * ND;
    u16* Kb   = Qb  + (size_t)NB * NH * SQ * DHN;
    u16* Vtb  = Kb  + (size_t)NB * NH * SKVN * DHN;
    u16* AOb  = Vtb + (size_t)NB * NH * SKVN * DHN;
    float* mbias = (float*)(AOb + (size_t)NB * SQ * ND);

    const dim3 blk(256);
    cvt_all<<<dim3(4628), blk, 0, stream>>>(x, mems, Wq, Wk, Wv, Wo,
                                            xb, memb, Wqb, Wkb, Wvb, Wob,
                                            mask, mbias);
    gemm_qkv<<<dim3(896), blk, 0, stream>>>(xb, memb,
                                            Wqb, bq, Qb,
                                            Wkb, bk, Kb,
                                            Wvb, bv, Vtb);
    attn_mfma<<<dim3(512), blk, 0, stream>>>(Qb, Kb, Vtb, mbias, AOb);
    gemm_o<<<dim3(512), blk, 0, stream>>>(AOb, Wob, bo, out);
}

// Round 13
// 164.022 us; speedup vs baseline: 1.1505x; 1.0104x over previous
//
#include <hip/hip_runtime.h>
#include <math.h>

#define NB   2
#define SQ   2048
#define SMEM 512
#define SKVN 2560
#define ND   1024
#define NH   16
#define DHN  64
#define NBH  32                     /* NB*NH */

typedef unsigned short u16;
typedef short bf16x8 __attribute__((ext_vector_type(8)));   // 8 bf16 = 4 VGPR
typedef float f32x4 __attribute__((ext_vector_type(4)));
typedef u16 u16x4 __attribute__((ext_vector_type(4)));
typedef u16 u16x8 __attribute__((ext_vector_type(8)));

#define CSC   0.1803368801111204f   /* 0.125 * log2(e) */

__device__ __forceinline__ u16 f2bf(float f) {             // RNE f32->bf16
    unsigned u = __float_as_uint(f);
    u += 0x7FFFu + ((u >> 16) & 1u);
    return (u16)(u >> 16);
}

__device__ __forceinline__ float bf2f(u16 v) {
    return __uint_as_float(((unsigned)v) << 16);
}

__device__ __forceinline__ void async16(u16* lds, const u16* g) {
    __builtin_amdgcn_global_load_lds(
        (const __attribute__((address_space(1))) void*)g,
        (__attribute__((address_space(3))) void*)lds, 16, 0, 0);
}

__device__ __forceinline__ unsigned lds_off(const void* p) {
    return (unsigned)(uintptr_t)(const __attribute__((address_space(3))) void*)p;
}

__device__ __forceinline__ u16x4 tr_read(unsigned a) {     // ds_read_b64_tr_b16
    u16x4 d;
    asm volatile("ds_read_b64_tr_b16 %0, %1" : "=v"(d) : "v"(a) : "memory");
    return d;
}

__device__ __forceinline__ unsigned cvtpk(float lo, float hi) {
    unsigned r;
    asm("v_cvt_pk_bf16_f32 %0, %1, %2" : "=v"(r) : "v"(lo), "v"(hi));
    return r;
}

__device__ __forceinline__ float exp2r(float x) {          // raw v_exp_f32
    float r;
    asm("v_exp_f32 %0, %1" : "=v"(r) : "v"(x));
    return r;
}

union PKU { unsigned u[2]; u16x4 v; };
union U8  { struct { u16x4 lo, hi; } p; bf16x8 v; };

// ---------------------------------------------------------------------------
// One launch: f32->bf16 for x, mems, Wq, Wk, Wv, Wo (+ mask -> bf16 log2-bias).
// ---------------------------------------------------------------------------
__global__ __launch_bounds__(256)
void cvt_all(const float* __restrict__ x, const float* __restrict__ mems,
             const float* __restrict__ W0, const float* __restrict__ W1,
             const float* __restrict__ W2, const float* __restrict__ W3,
             u16* __restrict__ xb, u16* __restrict__ memb,
             u16* __restrict__ d0, u16* __restrict__ d1,
             u16* __restrict__ d2, u16* __restrict__ d3,
             const int* __restrict__ mask, u16* __restrict__ mb16)
{
    const int bid = blockIdx.x;
    if (bid >= 4608) {                       // mask bias tail: 5120 elems
        const int i = (bid - 4608) * 256 + threadIdx.x;
        if (i < NB * SKVN)
            mb16[i] = mask[i] ? (u16)0 : f2bf(1.0e6f * CSC);
        return;
    }
    size_t i = ((size_t)bid * 256 + threadIdx.x) * 8;
    const float* s; u16* d;
    if (i < 4194304) { s = x; d = xb; }
    else if (i < 5242880) { s = mems; d = memb; i -= 4194304; }
    else {
        size_t off = i - 5242880;
        const int wi = (int)(off >> 20);
        i = off & 1048575;
        switch (wi) {
            case 0:  s = W0; d = d0; break;
            case 1:  s = W1; d = d1; break;
            case 2:  s = W2; d = d2; break;
            default: s = W3; d = d3; break;
        }
    }
    float4 a = *(const float4*)(s + i);
    float4 b = *(const float4*)(s + i + 4);
    u16x8 o;
    o[0]=f2bf(a.x); o[1]=f2bf(a.y); o[2]=f2bf(a.z); o[3]=f2bf(a.w);
    o[4]=f2bf(b.x); o[5]=f2bf(b.y); o[6]=f2bf(b.z); o[7]=f2bf(b.w);
    *(u16x8*)(d + i) = o;
}

// A-row pointer with fused [mems; x] concat (NB=2 hardcoded)
__device__ __forceinline__ const u16* arow_ptr(const u16* x, const u16* mems,
                                               int grow, int T, int memLen) {
    int b = grow >= T ? 1 : 0;
    int t = grow - b * T;
    if (memLen > 0 && t < memLen)
        return mems + ((size_t)(b * memLen + t)) * ND;
    return x + ((size_t)(b * (T - memLen) + (t - memLen))) * ND;
}

// ---------------------------------------------------------------------------
// bf16 GEMM body (R6 form, verified) — used by gemm_qkv.
// ---------------------------------------------------------------------------
__device__ __forceinline__
void gemm_body(const u16* __restrict__ x, const u16* __restrict__ mems,
               const u16* __restrict__ W, const float* __restrict__ bias,
               void* __restrict__ out, int T, int memLen, int mode,
               int bx, int by, u16* As0, u16* As1, u16* Bs0, u16* Bs1)
{
    u16* As[2] = {As0, As1};
    u16* Bs[2] = {Bs0, Bs1};

    const int tid  = threadIdx.x;
    const int wave = tid >> 6, lane = tid & 63;
    const int lg = lane >> 4, li = lane & 15;
    const int wr = (wave >> 1) * 64, wc = (wave & 1) * 64;
    const int row0 = bx * 128, col0 = by * 128;

    const int srow = lane >> 2;
    const int sslot = lane & 3;

    f32x4 acc[4][4];
    const f32x4 zf = {0.f, 0.f, 0.f, 0.f};
#pragma unroll
    for (int m = 0; m < 4; ++m)
#pragma unroll
        for (int n = 0; n < 4; ++n) acc[m][n] = zf;

    auto stage = [&](int c, int kt) {
        const int k0 = kt * 32;
#pragma unroll
        for (int ch = wave; ch < 8; ch += 4) {
            const int r = ch * 16 + srow;
            const int gs = sslot ^ ((r ^ (r >> 2)) & 3);
            async16(&As[c][ch * 512],
                    arow_ptr(x, mems, row0 + r, T, memLen) + k0 + gs * 8);
        }
#pragma unroll
        for (int ch = wave; ch < 8; ch += 4) {
            const int r = ch * 16 + srow;
            const int gs = sslot ^ ((r ^ (r >> 2)) & 3);
            async16(&Bs[c][ch * 512],
                    W + (size_t)(col0 + r) * ND + k0 + gs * 8);
        }
    };

    stage(0, 0);
    int cur = 0;
    for (int kt = 0; kt < 32; ++kt) {
        __syncthreads();
        if (kt + 1 < 32) stage(cur ^ 1, kt + 1);

        bf16x8 af[4], bfr[4];
#pragma unroll
        for (int m = 0; m < 4; ++m) {
            const int r = wr + m * 16 + li;
            af[m] = *(const bf16x8*)&As[cur][r * 32 + ((lg ^ ((r ^ (r >> 2)) & 3)) << 3)];
        }
#pragma unroll
        for (int n = 0; n < 4; ++n) {
            const int r = wc + n * 16 + li;
            bfr[n] = *(const bf16x8*)&Bs[cur][r * 32 + ((lg ^ ((r ^ (r >> 2)) & 3)) << 3)];
        }
#pragma unroll
        for (int m = 0; m < 4; ++m)
#pragma unroll
            for (int n = 0; n < 4; ++n)
                acc[m][n] = __builtin_amdgcn_mfma_f32_16x16x32_bf16(
                                af[m], bfr[n], acc[m][n], 0, 0, 0);
        cur ^= 1;
    }

#pragma unroll
    for (int n = 0; n < 4; ++n) {
        const int col = col0 + wc + n * 16 + li;
        const float bv = bias[col];
#pragma unroll
        for (int m = 0; m < 4; ++m) {
            const int rbase = row0 + wr + m * 16 + 4 * lg;
            if (mode == 1) {
                u16* o = (u16*)out;
                const int h = col >> 6, dh = col & 63;
#pragma unroll
                for (int r = 0; r < 4; ++r) {
                    const int grow = rbase + r;
                    const int b = grow >= T ? 1 : 0;
                    const int t = grow - b * T;
                    o[(((size_t)b * NH + h) * T + t) * DHN + dh] =
                        f2bf(acc[m][n][r] + bv);
                }
            } else {
                u16* o = (u16*)out;
                const int h = col >> 6, dh = col & 63;
                const int b = rbase >= T ? 1 : 0;
                const int t = rbase - b * T;
                u16x4 pk;
                pk[0] = f2bf(acc[m][n][0] + bv);
                pk[1] = f2bf(acc[m][n][1] + bv);
                pk[2] = f2bf(acc[m][n][2] + bv);
                pk[3] = f2bf(acc[m][n][3] + bv);
                *(u16x4*)&o[(((size_t)b * NH + h) * DHN + dh) * (size_t)T + t] = pk;
            }
        }
    }
}

// Merged Q+K+V projections: 896 wg, XCD-bijective swizzle, id-decoded.
__global__ __launch_bounds__(256)
void gemm_qkv(const u16* __restrict__ xb, const u16* __restrict__ memb,
              const u16* __restrict__ Wq, const float* __restrict__ bq, u16* Qb,
              const u16* __restrict__ Wk, const float* __restrict__ bk, u16* Kb,
              const u16* __restrict__ Wv, const float* __restrict__ bv, u16* Vtb)
{
    __shared__ u16 As[2][128 * 32];
    __shared__ u16 Bs[2][128 * 32];
    const int id = (blockIdx.x & 7) * 112 + (blockIdx.x >> 3);  // 896 = 8*112
    if (id < 256) {
        gemm_body(xb, nullptr, Wq, bq, Qb, SQ, 0, 1, id & 31, id >> 5,
                  As[0], As[1], Bs[0], Bs[1]);
    } else if (id < 576) {
        const int t = id - 256;
        gemm_body(xb, memb, Wk, bk, Kb, SKVN, SMEM, 1, t % 40, t / 40,
                  As[0], As[1], Bs[0], Bs[1]);
    } else {
        const int t = id - 576;
        gemm_body(xb, memb, Wv, bv, Vtb, SKVN, SMEM, 2, t % 40, t / 40,
                  As[0], As[1], Bs[0], Bs[1]);
    }
}

// ---------------------------------------------------------------------------
// O-projection: 64x128 tiles -> 512 wgs (R11, verified).
// ---------------------------------------------------------------------------
__global__ __launch_bounds__(256)
void gemm_o(const u16* __restrict__ x, const u16* __restrict__ W,
            const float* __restrict__ bias, float* __restrict__ out)
{
    __shared__ u16 As[2][64 * 32];
    __shared__ u16 Bs[2][128 * 32];

    const int tid  = threadIdx.x;
    const int wave = tid >> 6, lane = tid & 63;
    const int lg = lane >> 4, li = lane & 15;
    const int wr = (wave >> 1) * 32, wc = (wave & 1) * 64;

    const int id = (blockIdx.x & 7) * 64 + (blockIdx.x >> 3);   // 512 = 8*64
    const int row0 = (id >> 3) * 64, col0 = (id & 7) * 128;

    const int srow = lane >> 2;
    const int sslot = lane & 3;

    f32x4 acc[2][4];
    const f32x4 zf = {0.f, 0.f, 0.f, 0.f};
#pragma unroll
    for (int m = 0; m < 2; ++m)
#pragma unroll
        for (int n = 0; n < 4; ++n) acc[m][n] = zf;

    auto stage = [&](int c, int kt) {
        const int k0 = kt * 32;
        {   // A: 4 chunks of 16 rows; one per wave
            const int r = wave * 16 + srow;
            const int gs = sslot ^ ((r ^ (r >> 2)) & 3);
            async16(&As[c][wave * 512],
                    x + (size_t)(row0 + r) * ND + k0 + gs * 8);
        }
#pragma unroll
        for (int ch = wave; ch < 8; ch += 4) {   // B: 8 chunks; two per wave
            const int r = ch * 16 + srow;
            const int gs = sslot ^ ((r ^ (r >> 2)) & 3);
            async16(&Bs[c][ch * 512],
                    W + (size_t)(col0 + r) * ND + k0 + gs * 8);
        }
    };

    stage(0, 0);
    int cur = 0;
    for (int kt = 0; kt < 32; ++kt) {
        __syncthreads();
        if (kt + 1 < 32) stage(cur ^ 1, kt + 1);

        bf16x8 af[2], bfr[4];
#pragma unroll
        for (int m = 0; m < 2; ++m) {
            const int r = wr + m * 16 + li;
            af[m] = *(const bf16x8*)&As[cur][r * 32 + ((lg ^ ((r ^ (r >> 2)) & 3)) << 3)];
        }
#pragma unroll
        for (int n = 0; n < 4; ++n) {
            const int r = wc + n * 16 + li;
            bfr[n] = *(const bf16x8*)&Bs[cur][r * 32 + ((lg ^ ((r ^ (r >> 2)) & 3)) << 3)];
        }
#pragma unroll
        for (int m = 0; m < 2; ++m)
#pragma unroll
            for (int n = 0; n < 4; ++n)
                acc[m][n] = __builtin_amdgcn_mfma_f32_16x16x32_bf16(
                                af[m], bfr[n], acc[m][n], 0, 0, 0);
        cur ^= 1;
    }

#pragma unroll
    for (int n = 0; n < 4; ++n) {
        const int col = col0 + wc + n * 16 + li;
        const float bv = bias[col];
#pragma unroll
        for (int m = 0; m < 2; ++m) {
            const int rbase = row0 + wr + m * 16 + 4 * lg;
#pragma unroll
            for (int r = 0; r < 4; ++r)
                out[(size_t)(rbase + r) * ND + col] = acc[m][n][r] + bv;
        }
    }
}

// ---------------------------------------------------------------------------
// MFMA flash attention v9: counted-vmcnt 2-barrier pipeline with an EXACT
// vmem ledger. stage() = 4 vmem ops/wave; masks live in LDS (staged once
// behind __syncthreads) so the in-loop vmem stream is stage ops only.
// Iter t first barrier: vmcnt(4) (leaves stage(t+1) in flight); LAST iter
// peeled to vmcnt(0). Prologue order pinned with sched_barrier(0).
// ---------------------------------------------------------------------------
__global__ __launch_bounds__(256)
void attn_mfma(const u16* __restrict__ Qw, const u16* __restrict__ Kw,
               const u16* __restrict__ Vt, const u16* __restrict__ mb16,
               u16* __restrict__ AO)
{
    __shared__ u16 Ks[2][64 * 64];
    __shared__ u16 Vs[2][64 * 64];
    __shared__ u16 Ps[4][2048];          // per-wave: 2 P^T tiles [64 kv][16 q]
    __shared__ u16 Ms[SKVN];             // bf16 mask bias row (5 KB)

    const int tid  = threadIdx.x;
    const int wave = tid >> 6, lane = tid & 63;
    const int lg = lane >> 4, li = lane & 15;

    const int wg = blockIdx.x;                   // 512 wgs
    const int sw = (wg & 7) * 64 + (wg >> 3);    // XCD-contiguous chunks
    const int bh = sw >> 4;                      // 16 q-tiles per bh
    const int q0 = (sw & 15) * 128;
    const int b = bh >> 4, h = bh & 15;

    const u16* Kg = Kw + (size_t)bh * SKVN * DHN;
    const u16* Vg = Vt + (size_t)bh * DHN * SKVN;
    const u16* m16row = mb16 + (size_t)b * SKVN;

    // Q fragments: rows wave*32+li (half A) and +16 (half B)
    bf16x8 qA0, qA1, qB0, qB1;
    {
        const u16* Qp = Qw + ((size_t)bh * SQ + q0 + wave * 32 + li) * DHN;
        qA0 = *(const bf16x8*)(Qp + lg * 8);
        qA1 = *(const bf16x8*)(Qp + 32 + lg * 8);
        qB0 = *(const bf16x8*)(Qp + 16 * DHN + lg * 8);
        qB1 = *(const bf16x8*)(Qp + 16 * DHN + 32 + lg * 8);
    }

    // stage mask-bias row into LDS (one-time; fully drained by syncthreads)
    for (int i = tid * 8; i < SKVN; i += 2048)
        *(u16x8*)&Ms[i] = *(const u16x8*)(m16row + i);

    U8 ou;
#pragma unroll
    for (int i = 0; i < 4; ++i) { ou.p.lo[i] = 0x3F80; ou.p.hi[i] = 0x3F80; }
    const bf16x8 onesb = ou.v;

    const int srow = lane >> 3, sslot = lane & 7;

    auto stage = [&](int c, int t) {             // exactly 4 vmem ops per wave
        const int kv0 = t * 64;
#pragma unroll
        for (int ch = wave; ch < 8; ch += 4) {
            const int r = ch * 8 + srow;
            async16(&Ks[c][ch * 512],
                    Kg + (size_t)(kv0 + r) * DHN + ((sslot ^ (r & 7)) << 3));
        }
#pragma unroll
        for (int ch = wave; ch < 8; ch += 4) {
            const int r = ch * 8 + srow;
            async16(&Vs[c][ch * 512],
                    Vg + (size_t)r * SKVN + kv0 + ((sslot ^ (r & 7)) << 3));
        }
    };

    f32x4 oA[4], oB[4], laccA, laccB;
    const f32x4 zf = {0.f, 0.f, 0.f, 0.f};
#pragma unroll
    for (int n = 0; n < 4; ++n) { oA[n] = zf; oB[n] = zf; }
    laccA = zf; laccB = zf;

    u16* Pw = &Ps[wave][0];
    const unsigned paA = lds_off(Pw) + 256u * lg + 8u * li;
    const unsigned paB = paA + 2048u;            // half-B P^T tile

    // Drain EVERYTHING (Q loads, mask staging) so the ledger starts clean.
    __syncthreads();
    __builtin_amdgcn_sched_barrier(0);
    stage(0, 0);                                 // S0: 4 ops
    __builtin_amdgcn_sched_barrier(0);
    stage(1, 1);                                 // S1: 4 ops
    __builtin_amdgcn_sched_barrier(0);

    const int NT = SKVN / 64;
    int cur = 0;
    for (int t = 0; t < NT; ++t) {
        // Drain stage(t): outstanding = [S(t)(4), S(t+1)(4)] -> vmcnt(4).
        // Last iteration has no S(t+1) in flight -> full drain.
        if (t == NT - 1) asm volatile("s_waitcnt vmcnt(0)" ::: "memory");
        else             asm volatile("s_waitcnt vmcnt(4)" ::: "memory");
        __builtin_amdgcn_s_barrier();
        __builtin_amdgcn_sched_barrier(0);

        // mask bias for this tile from LDS (broadcast reads)
        float mbc[4];
#pragma unroll
        for (int n = 0; n < 4; ++n)
            mbc[n] = bf2f(Ms[t * 64 + n * 16 + li]);

        // ---- S = Q K^T for both halves (K frags read once) ----
        __builtin_amdgcn_s_setprio(1);
        f32x4 sA[4], sB[4];
#pragma unroll
        for (int n = 0; n < 4; ++n) {
            const int r = n * 16 + li;
            bf16x8 kb0 = *(const bf16x8*)&Ks[cur][r * 64 + ((lg ^ (r & 7)) << 3)];
            bf16x8 kb1 = *(const bf16x8*)&Ks[cur][r * 64 + (((4 + lg) ^ (r & 7)) << 3)];
            f32x4 z = zf;
            z     = __builtin_amdgcn_mfma_f32_16x16x32_bf16(qA0, kb0, z, 0, 0, 0);
            sA[n] = __builtin_amdgcn_mfma_f32_16x16x32_bf16(qA1, kb1, z, 0, 0, 0);
            f32x4 y = zf;
            y     = __builtin_amdgcn_mfma_f32_16x16x32_bf16(qB0, kb0, y, 0, 0, 0);
            sB[n] = __builtin_amdgcn_mfma_f32_16x16x32_bf16(qB1, kb1, y, 0, 0, 0);
        }
        __builtin_amdgcn_s_setprio(0);

        // ---- P = exp2(s*CSC - mb); pack to the two P^T tiles ----
#pragma unroll
        for (int n = 0; n < 4; ++n) {
            const float mb = mbc[n];
            const int pw = (n * 16 + li) * 16 + lg * 4;
            PKU ua;
            ua.u[0] = cvtpk(exp2r(fmaf(sA[n][0], CSC, -mb)),
                            exp2r(fmaf(sA[n][1], CSC, -mb)));
            ua.u[1] = cvtpk(exp2r(fmaf(sA[n][2], CSC, -mb)),
                            exp2r(fmaf(sA[n][3], CSC, -mb)));
            *(u16x4*)&Pw[pw] = ua.v;
            PKU ub;
            ub.u[0] = cvtpk(exp2r(fmaf(sB[n][0], CSC, -mb)),
                            exp2r(fmaf(sB[n][1], CSC, -mb)));
            ub.u[1] = cvtpk(exp2r(fmaf(sB[n][2], CSC, -mb)),
                            exp2r(fmaf(sB[n][3], CSC, -mb)));
            *(u16x4*)&Pw[1024 + pw] = ub.v;
        }

        // ---- PV: A-frags via hardware transpose reads of both P^T tiles ----
        u16x4 a00 = tr_read(paA);
        u16x4 a01 = tr_read(paA + 128);
        u16x4 a10 = tr_read(paA + 1024);
        u16x4 a11 = tr_read(paA + 1024 + 128);
        u16x4 b00 = tr_read(paB);
        u16x4 b01 = tr_read(paB + 128);
        u16x4 b10 = tr_read(paB + 1024);
        u16x4 b11 = tr_read(paB + 1024 + 128);
        asm volatile("s_waitcnt lgkmcnt(0)" ::: "memory");
        __builtin_amdgcn_sched_barrier(0);
        U8 pA0, pA1, pB0, pB1;
        pA0.p.lo = a00; pA0.p.hi = a01;
        pA1.p.lo = a10; pA1.p.hi = a11;
        pB0.p.lo = b00; pB0.p.hi = b01;
        pB1.p.lo = b10; pB1.p.hi = b11;

        __builtin_amdgcn_s_setprio(1);
        laccA = __builtin_amdgcn_mfma_f32_16x16x32_bf16(pA0.v, onesb, laccA, 0, 0, 0);
        laccA = __builtin_amdgcn_mfma_f32_16x16x32_bf16(pA1.v, onesb, laccA, 0, 0, 0);
        laccB = __builtin_amdgcn_mfma_f32_16x16x32_bf16(pB0.v, onesb, laccB, 0, 0, 0);
        laccB = __builtin_amdgcn_mfma_f32_16x16x32_bf16(pB1.v, onesb, laccB, 0, 0, 0);
#pragma unroll
        for (int n = 0; n < 4; ++n) {
            const int r = n * 16 + li;
            bf16x8 vb0 = *(const bf16x8*)&Vs[cur][r * 64 + ((lg ^ (r & 7)) << 3)];
            bf16x8 vb1 = *(const bf16x8*)&Vs[cur][r * 64 + (((4 + lg) ^ (r & 7)) << 3)];
            oA[n] = __builtin_amdgcn_mfma_f32_16x16x32_bf16(pA0.v, vb0, oA[n], 0, 0, 0);
            oA[n] = __builtin_amdgcn_mfma_f32_16x16x32_bf16(pA1.v, vb1, oA[n], 0, 0, 0);
            oB[n] = __builtin_amdgcn_mfma_f32_16x16x32_bf16(pB0.v, vb0, oB[n], 0, 0, 0);
            oB[n] = __builtin_amdgcn_mfma_f32_16x16x32_bf16(pB1.v, vb1, oB[n], 0, 0, 0);
        }
        __builtin_amdgcn_s_setprio(0);

        // all own LDS reads of buf[cur] complete -> free the buffer
        asm volatile("s_waitcnt lgkmcnt(0)" ::: "memory");
        __builtin_amdgcn_s_barrier();
        __builtin_amdgcn_sched_barrier(0);

        if (t + 2 < NT) stage(cur, t + 2);       // S(t+2): 4 ops into freed buf
        cur ^= 1;
    }

    // epilogue: AO[b, q, h*64+d] bf16 — halves A and B
#pragma unroll
    for (int r = 0; r < 4; ++r) {
        const float invA = 1.f / laccA[r];
        const float invB = 1.f / laccB[r];
        const int rowA = q0 + wave * 32 + 4 * lg + r;
#pragma unroll
        for (int n = 0; n < 4; ++n) {
            const int col = h * DHN + n * 16 + li;
            AO[((size_t)b * SQ + rowA) * ND + col] = f2bf(oA[n][r] * invA);
            AO[((size_t)b * SQ + rowA + 16) * ND + col] = f2bf(oB[n][r] * invB);
        }
    }
}

// ---------------------------------------------------------------------------
extern "C" void kernel_launch(void* const* d_in, const int* in_sizes, int n_in,
                              void* d_out, int out_size, void* d_ws, size_t ws_size,
                              hipStream_t stream)
{
    const float* x    = (const float*)d_in[0];
    const float* mems = (const float*)d_in[1];
    const int*   mask = (const int*)d_in[3];
    const float* Wq = (const float*)d_in[4];  const float* bq = (const float*)d_in[5];
    const float* Wk = (const float*)d_in[6];  const float* bk = (const float*)d_in[7];
    const float* Wv = (const float*)d_in[8];  const float* bv = (const float*)d_in[9];
    const float* Wo = (const float*)d_in[10]; const float* bo = (const float*)d_in[11];
    float* out = (float*)d_out;

    u16* ws = (u16*)d_ws;
    u16* xb   = ws;
    u16* memb = xb   + (size_t)NB * SQ * ND;
    u16* Wqb  = memb + (size_t)NB * SMEM * ND;
    u16* Wkb  = Wqb + (size_t)ND * ND;
    u16* Wvb  = Wkb + (size_t)ND * ND;
    u16* Wob  = Wvb + (size_t)ND * ND;
    u16* Qb   = Wob + (size_t)ND * ND;
    u16* Kb   = Qb  + (size_t)NB * NH * SQ * DHN;
    u16* Vtb  = Kb  + (size_t)NB * NH * SKVN * DHN;
    u16* AOb  = Vtb + (size_t)NB * NH * SKVN * DHN;
    u16* mb16 = AOb + (size_t)NB * SQ * ND;

    const dim3 blk(256);
    cvt_all<<<dim3(4628), blk, 0, stream>>>(x, mems, Wq, Wk, Wv, Wo,
                                            xb, memb, Wqb, Wkb, Wvb, Wob,
                                            mask, mb16);
    gemm_qkv<<<dim3(896), blk, 0, stream>>>(xb, memb,
                                            Wqb, bq, Qb,
                                            Wkb, bk, Kb,
                                            Wvb, bv, Vtb);
    attn_mfma<<<dim3(512), blk, 0, stream>>>(Qb, Kb, Vtb, mb16, AOb);
    gemm_o<<<dim3(512), blk, 0, stream>>>(AOb, Wob, bo, out);
}

// Round 14
// 161.831 us; speedup vs baseline: 1.1660x; 1.0135x over previous
//
#include <hip/hip_runtime.h>
#include <math.h>

#define NB   2
#define SQ   2048
#define SMEM 512
#define SKVN 2560
#define ND   1024
#define NH   16
#define DHN  64
#define NBH  32                     /* NB*NH */

typedef unsigned short u16;
typedef short bf16x8 __attribute__((ext_vector_type(8)));   // 8 bf16 = 4 VGPR
typedef float f32x4 __attribute__((ext_vector_type(4)));
typedef u16 u16x4 __attribute__((ext_vector_type(4)));
typedef u16 u16x8 __attribute__((ext_vector_type(8)));

#define CSC   0.1803368801111204f   /* 0.125 * log2(e) */

__device__ __forceinline__ u16 f2bf(float f) {             // RNE f32->bf16
    unsigned u = __float_as_uint(f);
    u += 0x7FFFu + ((u >> 16) & 1u);
    return (u16)(u >> 16);
}

__device__ __forceinline__ float bf2f(u16 v) {
    return __uint_as_float(((unsigned)v) << 16);
}

__device__ __forceinline__ void async16(u16* lds, const u16* g) {
    __builtin_amdgcn_global_load_lds(
        (const __attribute__((address_space(1))) void*)g,
        (__attribute__((address_space(3))) void*)lds, 16, 0, 0);
}

__device__ __forceinline__ unsigned lds_off(const void* p) {
    return (unsigned)(uintptr_t)(const __attribute__((address_space(3))) void*)p;
}

__device__ __forceinline__ u16x4 tr_read(unsigned a) {     // ds_read_b64_tr_b16
    u16x4 d;
    asm volatile("ds_read_b64_tr_b16 %0, %1" : "=v"(d) : "v"(a) : "memory");
    return d;
}

__device__ __forceinline__ unsigned cvtpk(float lo, float hi) {
    unsigned r;
    asm("v_cvt_pk_bf16_f32 %0, %1, %2" : "=v"(r) : "v"(lo), "v"(hi));
    return r;
}

__device__ __forceinline__ float exp2r(float x) {          // raw v_exp_f32
    float r;
    asm("v_exp_f32 %0, %1" : "=v"(r) : "v"(x));
    return r;
}

union PKU { unsigned u[2]; u16x4 v; };
union U8  { struct { u16x4 lo, hi; } p; bf16x8 v; };

// ---------------------------------------------------------------------------
// One launch: f32->bf16 for x, mems, Wq, Wk, Wv, Wo (+ mask -> bf16 log2-bias).
// ---------------------------------------------------------------------------
__global__ __launch_bounds__(256)
void cvt_all(const float* __restrict__ x, const float* __restrict__ mems,
             const float* __restrict__ W0, const float* __restrict__ W1,
             const float* __restrict__ W2, const float* __restrict__ W3,
             u16* __restrict__ xb, u16* __restrict__ memb,
             u16* __restrict__ d0, u16* __restrict__ d1,
             u16* __restrict__ d2, u16* __restrict__ d3,
             const int* __restrict__ mask, u16* __restrict__ mb16)
{
    const int bid = blockIdx.x;
    if (bid >= 4608) {                       // mask bias tail: 5120 elems
        const int i = (bid - 4608) * 256 + threadIdx.x;
        if (i < NB * SKVN)
            mb16[i] = mask[i] ? (u16)0 : f2bf(1.0e6f * CSC);
        return;
    }
    size_t i = ((size_t)bid * 256 + threadIdx.x) * 8;
    const float* s; u16* d;
    if (i < 4194304) { s = x; d = xb; }
    else if (i < 5242880) { s = mems; d = memb; i -= 4194304; }
    else {
        size_t off = i - 5242880;
        const int wi = (int)(off >> 20);
        i = off & 1048575;
        switch (wi) {
            case 0:  s = W0; d = d0; break;
            case 1:  s = W1; d = d1; break;
            case 2:  s = W2; d = d2; break;
            default: s = W3; d = d3; break;
        }
    }
    float4 a = *(const float4*)(s + i);
    float4 b = *(const float4*)(s + i + 4);
    u16x8 o;
    o[0]=f2bf(a.x); o[1]=f2bf(a.y); o[2]=f2bf(a.z); o[3]=f2bf(a.w);
    o[4]=f2bf(b.x); o[5]=f2bf(b.y); o[6]=f2bf(b.z); o[7]=f2bf(b.w);
    *(u16x8*)(d + i) = o;
}

// A-row pointer with fused [mems; x] concat (NB=2 hardcoded)
__device__ __forceinline__ const u16* arow_ptr(const u16* x, const u16* mems,
                                               int grow, int T, int memLen) {
    int b = grow >= T ? 1 : 0;
    int t = grow - b * T;
    if (memLen > 0 && t < memLen)
        return mems + ((size_t)(b * memLen + t)) * ND;
    return x + ((size_t)(b * (T - memLen) + (t - memLen))) * ND;
}

// ---------------------------------------------------------------------------
// bf16 GEMM body (R6 form, verified) — used by gemm_qkv.
// ---------------------------------------------------------------------------
__device__ __forceinline__
void gemm_body(const u16* __restrict__ x, const u16* __restrict__ mems,
               const u16* __restrict__ W, const float* __restrict__ bias,
               void* __restrict__ out, int T, int memLen, int mode,
               int bx, int by, u16* As0, u16* As1, u16* Bs0, u16* Bs1)
{
    u16* As[2] = {As0, As1};
    u16* Bs[2] = {Bs0, Bs1};

    const int tid  = threadIdx.x;
    const int wave = tid >> 6, lane = tid & 63;
    const int lg = lane >> 4, li = lane & 15;
    const int wr = (wave >> 1) * 64, wc = (wave & 1) * 64;
    const int row0 = bx * 128, col0 = by * 128;

    const int srow = lane >> 2;
    const int sslot = lane & 3;

    f32x4 acc[4][4];
    const f32x4 zf = {0.f, 0.f, 0.f, 0.f};
#pragma unroll
    for (int m = 0; m < 4; ++m)
#pragma unroll
        for (int n = 0; n < 4; ++n) acc[m][n] = zf;

    auto stage = [&](int c, int kt) {
        const int k0 = kt * 32;
#pragma unroll
        for (int ch = wave; ch < 8; ch += 4) {
            const int r = ch * 16 + srow;
            const int gs = sslot ^ ((r ^ (r >> 2)) & 3);
            async16(&As[c][ch * 512],
                    arow_ptr(x, mems, row0 + r, T, memLen) + k0 + gs * 8);
        }
#pragma unroll
        for (int ch = wave; ch < 8; ch += 4) {
            const int r = ch * 16 + srow;
            const int gs = sslot ^ ((r ^ (r >> 2)) & 3);
            async16(&Bs[c][ch * 512],
                    W + (size_t)(col0 + r) * ND + k0 + gs * 8);
        }
    };

    stage(0, 0);
    int cur = 0;
    for (int kt = 0; kt < 32; ++kt) {
        __syncthreads();
        if (kt + 1 < 32) stage(cur ^ 1, kt + 1);

        bf16x8 af[4], bfr[4];
#pragma unroll
        for (int m = 0; m < 4; ++m) {
            const int r = wr + m * 16 + li;
            af[m] = *(const bf16x8*)&As[cur][r * 32 + ((lg ^ ((r ^ (r >> 2)) & 3)) << 3)];
        }
#pragma unroll
        for (int n = 0; n < 4; ++n) {
            const int r = wc + n * 16 + li;
            bfr[n] = *(const bf16x8*)&Bs[cur][r * 32 + ((lg ^ ((r ^ (r >> 2)) & 3)) << 3)];
        }
#pragma unroll
        for (int m = 0; m < 4; ++m)
#pragma unroll
            for (int n = 0; n < 4; ++n)
                acc[m][n] = __builtin_amdgcn_mfma_f32_16x16x32_bf16(
                                af[m], bfr[n], acc[m][n], 0, 0, 0);
        cur ^= 1;
    }

#pragma unroll
    for (int n = 0; n < 4; ++n) {
        const int col = col0 + wc + n * 16 + li;
        const float bv = bias[col];
#pragma unroll
        for (int m = 0; m < 4; ++m) {
            const int rbase = row0 + wr + m * 16 + 4 * lg;
            if (mode == 1) {
                u16* o = (u16*)out;
                const int h = col >> 6, dh = col & 63;
#pragma unroll
                for (int r = 0; r < 4; ++r) {
                    const int grow = rbase + r;
                    const int b = grow >= T ? 1 : 0;
                    const int t = grow - b * T;
                    o[(((size_t)b * NH + h) * T + t) * DHN + dh] =
                        f2bf(acc[m][n][r] + bv);
                }
            } else {
                u16* o = (u16*)out;
                const int h = col >> 6, dh = col & 63;
                const int b = rbase >= T ? 1 : 0;
                const int t = rbase - b * T;
                u16x4 pk;
                pk[0] = f2bf(acc[m][n][0] + bv);
                pk[1] = f2bf(acc[m][n][1] + bv);
                pk[2] = f2bf(acc[m][n][2] + bv);
                pk[3] = f2bf(acc[m][n][3] + bv);
                *(u16x4*)&o[(((size_t)b * NH + h) * DHN + dh) * (size_t)T + t] = pk;
            }
        }
    }
}

// Merged Q+K+V projections: 896 wg, XCD-bijective swizzle, id-decoded.
__global__ __launch_bounds__(256)
void gemm_qkv(const u16* __restrict__ xb, const u16* __restrict__ memb,
              const u16* __restrict__ Wq, const float* __restrict__ bq, u16* Qb,
              const u16* __restrict__ Wk, const float* __restrict__ bk, u16* Kb,
              const u16* __restrict__ Wv, const float* __restrict__ bv, u16* Vtb)
{
    __shared__ u16 As[2][128 * 32];
    __shared__ u16 Bs[2][128 * 32];
    const int id = (blockIdx.x & 7) * 112 + (blockIdx.x >> 3);  // 896 = 8*112
    if (id < 256) {
        gemm_body(xb, nullptr, Wq, bq, Qb, SQ, 0, 1, id & 31, id >> 5,
                  As[0], As[1], Bs[0], Bs[1]);
    } else if (id < 576) {
        const int t = id - 256;
        gemm_body(xb, memb, Wk, bk, Kb, SKVN, SMEM, 1, t % 40, t / 40,
                  As[0], As[1], Bs[0], Bs[1]);
    } else {
        const int t = id - 576;
        gemm_body(xb, memb, Wv, bv, Vtb, SKVN, SMEM, 2, t % 40, t / 40,
                  As[0], As[1], Bs[0], Bs[1]);
    }
}

// ---------------------------------------------------------------------------
// O-projection: 64x128 tiles -> 512 wgs (R11, verified).
// ---------------------------------------------------------------------------
__global__ __launch_bounds__(256)
void gemm_o(const u16* __restrict__ x, const u16* __restrict__ W,
            const float* __restrict__ bias, float* __restrict__ out)
{
    __shared__ u16 As[2][64 * 32];
    __shared__ u16 Bs[2][128 * 32];

    const int tid  = threadIdx.x;
    const int wave = tid >> 6, lane = tid & 63;
    const int lg = lane >> 4, li = lane & 15;
    const int wr = (wave >> 1) * 32, wc = (wave & 1) * 64;

    const int id = (blockIdx.x & 7) * 64 + (blockIdx.x >> 3);   // 512 = 8*64
    const int row0 = (id >> 3) * 64, col0 = (id & 7) * 128;

    const int srow = lane >> 2;
    const int sslot = lane & 3;

    f32x4 acc[2][4];
    const f32x4 zf = {0.f, 0.f, 0.f, 0.f};
#pragma unroll
    for (int m = 0; m < 2; ++m)
#pragma unroll
        for (int n = 0; n < 4; ++n) acc[m][n] = zf;

    auto stage = [&](int c, int kt) {
        const int k0 = kt * 32;
        {   // A: 4 chunks of 16 rows; one per wave
            const int r = wave * 16 + srow;
            const int gs = sslot ^ ((r ^ (r >> 2)) & 3);
            async16(&As[c][wave * 512],
                    x + (size_t)(row0 + r) * ND + k0 + gs * 8);
        }
#pragma unroll
        for (int ch = wave; ch < 8; ch += 4) {   // B: 8 chunks; two per wave
            const int r = ch * 16 + srow;
            const int gs = sslot ^ ((r ^ (r >> 2)) & 3);
            async16(&Bs[c][ch * 512],
                    W + (size_t)(col0 + r) * ND + k0 + gs * 8);
        }
    };

    stage(0, 0);
    int cur = 0;
    for (int kt = 0; kt < 32; ++kt) {
        __syncthreads();
        if (kt + 1 < 32) stage(cur ^ 1, kt + 1);

        bf16x8 af[2], bfr[4];
#pragma unroll
        for (int m = 0; m < 2; ++m) {
            const int r = wr + m * 16 + li;
            af[m] = *(const bf16x8*)&As[cur][r * 32 + ((lg ^ ((r ^ (r >> 2)) & 3)) << 3)];
        }
#pragma unroll
        for (int n = 0; n < 4; ++n) {
            const int r = wc + n * 16 + li;
            bfr[n] = *(const bf16x8*)&Bs[cur][r * 32 + ((lg ^ ((r ^ (r >> 2)) & 3)) << 3)];
        }
#pragma unroll
        for (int m = 0; m < 2; ++m)
#pragma unroll
            for (int n = 0; n < 4; ++n)
                acc[m][n] = __builtin_amdgcn_mfma_f32_16x16x32_bf16(
                                af[m], bfr[n], acc[m][n], 0, 0, 0);
        cur ^= 1;
    }

#pragma unroll
    for (int n = 0; n < 4; ++n) {
        const int col = col0 + wc + n * 16 + li;
        const float bv = bias[col];
#pragma unroll
        for (int m = 0; m < 2; ++m) {
            const int rbase = row0 + wr + m * 16 + 4 * lg;
#pragma unroll
            for (int r = 0; r < 4; ++r)
                out[(size_t)(rbase + r) * ND + col] = acc[m][n][r] + bv;
        }
    }
}

// ---------------------------------------------------------------------------
// MFMA flash attention v10: 8 waves / 512 threads, Q-tile 256 rows/block,
// 256 blocks -> 2 blocks/CU = 4 waves/SIMD (2x TLP). 8 waves share each
// 64x64 K/V tile: stage() = 2 vmem ops/wave (ledger: vmcnt(2), last iter 0).
// Per-wave math identical to verified R13 kernel.
// ---------------------------------------------------------------------------
__global__ __launch_bounds__(512)
void attn_mfma(const u16* __restrict__ Qw, const u16* __restrict__ Kw,
               const u16* __restrict__ Vt, const u16* __restrict__ mb16,
               u16* __restrict__ AO)
{
    __shared__ u16 Ks[2][64 * 64];
    __shared__ u16 Vs[2][64 * 64];
    __shared__ u16 Ps[8][2048];          // per-wave: 2 P^T tiles [64 kv][16 q]
    __shared__ u16 Ms[SKVN];             // bf16 mask bias row (5 KB)

    const int tid  = threadIdx.x;
    const int wave = tid >> 6, lane = tid & 63;
    const int lg = lane >> 4, li = lane & 15;

    const int wg = blockIdx.x;                   // 256 wgs
    const int sw = (wg & 7) * 32 + (wg >> 3);    // XCD-contiguous chunks
    const int bh = sw >> 3;                      // 8 q-tiles per bh
    const int q0 = (sw & 7) * 256;
    const int b = bh >> 4, h = bh & 15;

    const u16* Kg = Kw + (size_t)bh * SKVN * DHN;
    const u16* Vg = Vt + (size_t)bh * DHN * SKVN;
    const u16* m16row = mb16 + (size_t)b * SKVN;

    // Q fragments: rows q0 + wave*32 + li (half A) and +16 (half B)
    bf16x8 qA0, qA1, qB0, qB1;
    {
        const u16* Qp = Qw + ((size_t)bh * SQ + q0 + wave * 32 + li) * DHN;
        qA0 = *(const bf16x8*)(Qp + lg * 8);
        qA1 = *(const bf16x8*)(Qp + 32 + lg * 8);
        qB0 = *(const bf16x8*)(Qp + 16 * DHN + lg * 8);
        qB1 = *(const bf16x8*)(Qp + 16 * DHN + 32 + lg * 8);
    }

    // stage mask-bias row into LDS (one-time; fully drained by syncthreads)
    for (int i = tid * 8; i < SKVN; i += 4096)
        *(u16x8*)&Ms[i] = *(const u16x8*)(m16row + i);

    U8 ou;
#pragma unroll
    for (int i = 0; i < 4; ++i) { ou.p.lo[i] = 0x3F80; ou.p.hi[i] = 0x3F80; }
    const bf16x8 onesb = ou.v;

    const int srow = lane >> 3, sslot = lane & 7;

    auto stage = [&](int c, int t) {             // exactly 2 vmem ops per wave
        const int kv0 = t * 64;
        const int r = wave * 8 + srow;           // 8 waves cover 8 chunks
        async16(&Ks[c][wave * 512],
                Kg + (size_t)(kv0 + r) * DHN + ((sslot ^ (r & 7)) << 3));
        async16(&Vs[c][wave * 512],
                Vg + (size_t)r * SKVN + kv0 + ((sslot ^ (r & 7)) << 3));
    };

    f32x4 oA[4], oB[4], laccA, laccB;
    const f32x4 zf = {0.f, 0.f, 0.f, 0.f};
#pragma unroll
    for (int n = 0; n < 4; ++n) { oA[n] = zf; oB[n] = zf; }
    laccA = zf; laccB = zf;

    u16* Pw = &Ps[wave][0];
    const unsigned paA = lds_off(Pw) + 256u * lg + 8u * li;
    const unsigned paB = paA + 2048u;            // half-B P^T tile

    // Drain EVERYTHING (Q loads, mask staging) so the ledger starts clean.
    __syncthreads();
    __builtin_amdgcn_sched_barrier(0);
    stage(0, 0);                                 // S0: 2 ops
    __builtin_amdgcn_sched_barrier(0);
    stage(1, 1);                                 // S1: 2 ops
    __builtin_amdgcn_sched_barrier(0);

    const int NT = SKVN / 64;
    int cur = 0;
    for (int t = 0; t < NT; ++t) {
        // Drain stage(t): outstanding = [S(t)(2), S(t+1)(2)] -> vmcnt(2).
        // Last iteration has no S(t+1) in flight -> full drain.
        if (t == NT - 1) asm volatile("s_waitcnt vmcnt(0)" ::: "memory");
        else             asm volatile("s_waitcnt vmcnt(2)" ::: "memory");
        __builtin_amdgcn_s_barrier();
        __builtin_amdgcn_sched_barrier(0);

        // mask bias for this tile from LDS (broadcast reads)
        float mbc[4];
#pragma unroll
        for (int n = 0; n < 4; ++n)
            mbc[n] = bf2f(Ms[t * 64 + n * 16 + li]);

        // ---- S = Q K^T for both halves (K frags read once) ----
        __builtin_amdgcn_s_setprio(1);
        f32x4 sA[4], sB[4];
#pragma unroll
        for (int n = 0; n < 4; ++n) {
            const int r = n * 16 + li;
            bf16x8 kb0 = *(const bf16x8*)&Ks[cur][r * 64 + ((lg ^ (r & 7)) << 3)];
            bf16x8 kb1 = *(const bf16x8*)&Ks[cur][r * 64 + (((4 + lg) ^ (r & 7)) << 3)];
            f32x4 z = zf;
            z     = __builtin_amdgcn_mfma_f32_16x16x32_bf16(qA0, kb0, z, 0, 0, 0);
            sA[n] = __builtin_amdgcn_mfma_f32_16x16x32_bf16(qA1, kb1, z, 0, 0, 0);
            f32x4 y = zf;
            y     = __builtin_amdgcn_mfma_f32_16x16x32_bf16(qB0, kb0, y, 0, 0, 0);
            sB[n] = __builtin_amdgcn_mfma_f32_16x16x32_bf16(qB1, kb1, y, 0, 0, 0);
        }
        __builtin_amdgcn_s_setprio(0);

        // ---- P = exp2(s*CSC - mb); pack to the two P^T tiles ----
#pragma unroll
        for (int n = 0; n < 4; ++n) {
            const float mb = mbc[n];
            const int pw = (n * 16 + li) * 16 + lg * 4;
            PKU ua;
            ua.u[0] = cvtpk(exp2r(fmaf(sA[n][0], CSC, -mb)),
                            exp2r(fmaf(sA[n][1], CSC, -mb)));
            ua.u[1] = cvtpk(exp2r(fmaf(sA[n][2], CSC, -mb)),
                            exp2r(fmaf(sA[n][3], CSC, -mb)));
            *(u16x4*)&Pw[pw] = ua.v;
            PKU ub;
            ub.u[0] = cvtpk(exp2r(fmaf(sB[n][0], CSC, -mb)),
                            exp2r(fmaf(sB[n][1], CSC, -mb)));
            ub.u[1] = cvtpk(exp2r(fmaf(sB[n][2], CSC, -mb)),
                            exp2r(fmaf(sB[n][3], CSC, -mb)));
            *(u16x4*)&Pw[1024 + pw] = ub.v;
        }

        // ---- PV: A-frags via hardware transpose reads of both P^T tiles ----
        u16x4 a00 = tr_read(paA);
        u16x4 a01 = tr_read(paA + 128);
        u16x4 a10 = tr_read(paA + 1024);
        u16x4 a11 = tr_read(paA + 1024 + 128);
        u16x4 b00 = tr_read(paB);
        u16x4 b01 = tr_read(paB + 128);
        u16x4 b10 = tr_read(paB + 1024);
        u16x4 b11 = tr_read(paB + 1024 + 128);
        asm volatile("s_waitcnt lgkmcnt(0)" ::: "memory");
        __builtin_amdgcn_sched_barrier(0);
        U8 pA0, pA1, pB0, pB1;
        pA0.p.lo = a00; pA0.p.hi = a01;
        pA1.p.lo = a10; pA1.p.hi = a11;
        pB0.p.lo = b00; pB0.p.hi = b01;
        pB1.p.lo = b10; pB1.p.hi = b11;

        __builtin_amdgcn_s_setprio(1);
        laccA = __builtin_amdgcn_mfma_f32_16x16x32_bf16(pA0.v, onesb, laccA, 0, 0, 0);
        laccA = __builtin_amdgcn_mfma_f32_16x16x32_bf16(pA1.v, onesb, laccA, 0, 0, 0);
        laccB = __builtin_amdgcn_mfma_f32_16x16x32_bf16(pB0.v, onesb, laccB, 0, 0, 0);
        laccB = __builtin_amdgcn_mfma_f32_16x16x32_bf16(pB1.v, onesb, laccB, 0, 0, 0);
#pragma unroll
        for (int n = 0; n < 4; ++n) {
            const int r = n * 16 + li;
            bf16x8 vb0 = *(const bf16x8*)&Vs[cur][r * 64 + ((lg ^ (r & 7)) << 3)];
            bf16x8 vb1 = *(const bf16x8*)&Vs[cur][r * 64 + (((4 + lg) ^ (r & 7)) << 3)];
            oA[n] = __builtin_amdgcn_mfma_f32_16x16x32_bf16(pA0.v, vb0, oA[n], 0, 0, 0);
            oA[n] = __builtin_amdgcn_mfma_f32_16x16x32_bf16(pA1.v, vb1, oA[n], 0, 0, 0);
            oB[n] = __builtin_amdgcn_mfma_f32_16x16x32_bf16(pB0.v, vb0, oB[n], 0, 0, 0);
            oB[n] = __builtin_amdgcn_mfma_f32_16x16x32_bf16(pB1.v, vb1, oB[n], 0, 0, 0);
        }
        __builtin_amdgcn_s_setprio(0);

        // all own LDS reads of buf[cur] complete -> free the buffer
        asm volatile("s_waitcnt lgkmcnt(0)" ::: "memory");
        __builtin_amdgcn_s_barrier();
        __builtin_amdgcn_sched_barrier(0);

        if (t + 2 < NT) stage(cur, t + 2);       // S(t+2): 2 ops into freed buf
        cur ^= 1;
    }

    // epilogue: AO[b, q, h*64+d] bf16 — halves A and B
#pragma unroll
    for (int r = 0; r < 4; ++r) {
        const float invA = 1.f / laccA[r];
        const float invB = 1.f / laccB[r];
        const int rowA = q0 + wave * 32 + 4 * lg + r;
#pragma unroll
        for (int n = 0; n < 4; ++n) {
            const int col = h * DHN + n * 16 + li;
            AO[((size_t)b * SQ + rowA) * ND + col] = f2bf(oA[n][r] * invA);
            AO[((size_t)b * SQ + rowA + 16) * ND + col] = f2bf(oB[n][r] * invB);
        }
    }
}

// ---------------------------------------------------------------------------
extern "C" void kernel_launch(void* const* d_in, const int* in_sizes, int n_in,
                              void* d_out, int out_size, void* d_ws, size_t ws_size,
                              hipStream_t stream)
{
    const float* x    = (const float*)d_in[0];
    const float* mems = (const float*)d_in[1];
    const int*   mask = (const int*)d_in[3];
    const float* Wq = (const float*)d_in[4];  const float* bq = (const float*)d_in[5];
    const float* Wk = (const float*)d_in[6];  const float* bk = (const float*)d_in[7];
    const float* Wv = (const float*)d_in[8];  const float* bv = (const float*)d_in[9];
    const float* Wo = (const float*)d_in[10]; const float* bo = (const float*)d_in[11];
    float* out = (float*)d_out;

    u16* ws = (u16*)d_ws;
    u16* xb   = ws;
    u16* memb = xb   + (size_t)NB * SQ * ND;
    u16* Wqb  = memb + (size_t)NB * SMEM * ND;
    u16* Wkb  = Wqb + (size_t)ND * ND;
    u16* Wvb  = Wkb + (size_t)ND * ND;
    u16* Wob  = Wvb + (size_t)ND * ND;
    u16* Qb   = Wob + (size_t)ND * ND;
    u16* Kb   = Qb  + (size_t)NB * NH * SQ * DHN;
    u16* Vtb  = Kb  + (size_t)NB * NH * SKVN * DHN;
    u16* AOb  = Vtb + (size_t)NB * NH * SKVN * DHN;
    u16* mb16 = AOb + (size_t)NB * SQ * ND;

    const dim3 blk(256);
    cvt_all<<<dim3(4628), blk, 0, stream>>>(x, mems, Wq, Wk, Wv, Wo,
                                            xb, memb, Wqb, Wkb, Wvb, Wob,
                                            mask, mb16);
    gemm_qkv<<<dim3(896), blk, 0, stream>>>(xb, memb,
                                            Wqb, bq, Qb,
                                            Wkb, bk, Kb,
                                            Wvb, bv, Vtb);
    attn_mfma<<<dim3(256), dim3(512), 0, stream>>>(Qb, Kb, Vtb, mb16, AOb);
    gemm_o<<<dim3(512), blk, 0, stream>>>(AOb, Wob, bo, out);
}